// Round 12
// baseline (4175.636 us; speedup 1.0000x reference)
//
#include <hip/hip_runtime.h>

// ---------------------------------------------------------------------------
// GPT encoder-decoder forward on MI355X (gfx950).
// Round 12: revert R11's PIPE3 (occupancy loss > depth gain).  R10 config
// restored; LM head and CQKV get MINW=5 (5 blocks/CU — LDS allows exactly
// 160KB/32KB; VGPR 56 << 102 cap).  Everything else identical to R10 (best).
// ---------------------------------------------------------------------------

typedef __bf16 bf16x8 __attribute__((ext_vector_type(8)));
typedef float  f32x4  __attribute__((ext_vector_type(4)));
typedef unsigned short u16x4 __attribute__((ext_vector_type(4)));
typedef unsigned short u16x8 __attribute__((ext_vector_type(8)));

constexpr int Lc = 6, Dc = 768, Hc = 12, HDc = 64, Vc = 32000;
constexpr int Bc = 4, Tc = 1024, FFc = 3072;
constexpr int Mtot = Bc * Tc;  // 4096

static __device__ __forceinline__ unsigned short f2bf(float f) {
  union { float f; unsigned u; } x; x.f = f;
  unsigned r = x.u + 0x7fffu + ((x.u >> 16) & 1u);   // RNE
  return (unsigned short)(r >> 16);
}
static __device__ __forceinline__ float bf2f(unsigned short s) {
  union { unsigned u; float f; } c; c.u = (unsigned)s << 16; return c.f;
}

static __device__ __forceinline__ void gl_lds16(const unsigned short* g, unsigned short* l) {
  __builtin_amdgcn_global_load_lds(
      (const __attribute__((address_space(1))) unsigned int*)g,
      (__attribute__((address_space(3))) unsigned int*)l, 16, 0, 0);
}

template <int N> static __device__ __forceinline__ void wait_vm() {
  if constexpr (N == 0)       asm volatile("s_waitcnt vmcnt(0)" ::: "memory");
  else if constexpr (N == 2)  asm volatile("s_waitcnt vmcnt(2)" ::: "memory");
  else if constexpr (N == 3)  asm volatile("s_waitcnt vmcnt(3)" ::: "memory");
  else if constexpr (N == 4)  asm volatile("s_waitcnt vmcnt(4)" ::: "memory");
  else if constexpr (N == 6)  asm volatile("s_waitcnt vmcnt(6)" ::: "memory");
  else if constexpr (N == 8)  asm volatile("s_waitcnt vmcnt(8)" ::: "memory");
}

// ---------------------------------------------------------------------------
// Block reductions (256 threads = 4 waves)
// ---------------------------------------------------------------------------
static __device__ __forceinline__ float blockReduceSum(float v, float* red) {
  #pragma unroll
  for (int o = 32; o; o >>= 1) v += __shfl_xor(v, o, 64);
  int w = threadIdx.x >> 6;
  __syncthreads();
  if ((threadIdx.x & 63) == 0) red[w] = v;
  __syncthreads();
  return red[0] + red[1] + red[2] + red[3];
}

// ---------------------------------------------------------------------------
// Mega weight transpose+convert: all 11 weight groups in ONE dispatch.
// ---------------------------------------------------------------------------
struct WcTab {
  const float* src[11];
  unsigned short* dst[11];
  int Kt[11], Nt[11];
  int start[12];
};

__global__ __launch_bounds__(256) void wconv_all_k(WcTab tab) {
  __shared__ float t[32][33];
  const int tb = blockIdx.x;
  int e = 0;
  #pragma unroll
  for (int i = 1; i < 11; i++) if (tb >= tab.start[i]) e = i;
  const int local = tb - tab.start[e];
  const int Kt = tab.Kt[e], Nt = tab.Nt[e];
  const int per = Kt * Nt;
  const int z = local / per;
  const int rem = local - z * per;
  const int k0 = (rem / Nt) * 32, n0 = (rem % Nt) * 32;
  const int K = Kt * 32, N = Nt * 32;
  const float* W = tab.src[e] + (long)z * K * N;
  unsigned short* WT = tab.dst[e] + (long)z * K * N;

  const int tid = threadIdx.x;
  const int rr = tid >> 3;
  const int cc = (tid & 7) * 4;
  f32x4 v = *reinterpret_cast<const f32x4*>(W + (long)(k0 + rr) * N + n0 + cc);
  #pragma unroll
  for (int j = 0; j < 4; j++) t[rr][cc + j] = v[j];
  __syncthreads();
  u16x4 o;
  #pragma unroll
  for (int j = 0; j < 4; j++) o[j] = f2bf(t[cc + j][rr]);
  *reinterpret_cast<u16x4*>(WT + (long)(n0 + rr) * K + k0 + cc) = o;
}

// ---------------------------------------------------------------------------
// V transpose: vb bf16 [B*T][D] (head h cols) -> vT bf16 [B*H][HD][T]
// ---------------------------------------------------------------------------
__global__ __launch_bounds__(256) void vtrans_k(const unsigned short* __restrict__ V,
                                                unsigned short* __restrict__ VT) {
  __shared__ unsigned short t[64][65];
  const int bh = blockIdx.y;
  const int b = bh / Hc, h = bh % Hc;
  const int t0 = blockIdx.x * 64;
  const int tid = threadIdx.x;
  const int rr = tid >> 3;
  const int c8 = (tid & 7) * 8;
  #pragma unroll
  for (int rep = 0; rep < 2; rep++) {
    int row = rep * 32 + rr;
    u16x8 v = *reinterpret_cast<const u16x8*>(V + (long)(b * Tc + t0 + row) * Dc + h * HDc + c8);
    #pragma unroll
    for (int j = 0; j < 8; j++) t[row][c8 + j] = v[j];
  }
  __syncthreads();
  #pragma unroll
  for (int rep = 0; rep < 2; rep++) {
    int hd = rep * 32 + rr;
    u16x8 o;
    #pragma unroll
    for (int j = 0; j < 8; j++) o[j] = t[c8 + j][hd];
    *reinterpret_cast<u16x8*>(VT + ((long)bh * HDc + hd) * Tc + t0 + c8) = o;
  }
}

// ---------------------------------------------------------------------------
// Embedding
// ---------------------------------------------------------------------------
__global__ __launch_bounds__(256) void embed_k(const int* __restrict__ idx,
                                               const float* __restrict__ tok,
                                               const float* __restrict__ pos,
                                               float* __restrict__ out) {
  const long row = blockIdx.x;
  const int t = (int)(row % Tc);
  const long id = idx[row];
  #pragma unroll
  for (int j = 0; j < 3; j++) {
    int e = threadIdx.x + j * 256;
    out[row * Dc + e] = tok[id * Dc + e] + pos[(long)t * Dc + e];
  }
}

// ---------------------------------------------------------------------------
// LayerNorm over D=768, output bf16
// ---------------------------------------------------------------------------
__global__ __launch_bounds__(256) void ln_k(const float* __restrict__ X,
                                            const float* __restrict__ g,
                                            const float* __restrict__ bta,
                                            unsigned short* __restrict__ out) {
  __shared__ float red[4];
  const long row = blockIdx.x;
  const int tid = threadIdx.x;
  float v[3];
  #pragma unroll
  for (int j = 0; j < 3; j++) v[j] = X[row * Dc + tid + j * 256];
  float s = v[0] + v[1] + v[2];
  s = blockReduceSum(s, red);
  float mean = s * (1.f / 768.f);
  float q = 0.f;
  #pragma unroll
  for (int j = 0; j < 3; j++) { float d = v[j] - mean; q += d * d; }
  q = blockReduceSum(q, red);
  float rstd = rsqrtf(q * (1.f / 768.f) + 1e-5f);
  #pragma unroll
  for (int j = 0; j < 3; j++) {
    int e = tid + j * 256;
    out[row * Dc + e] = f2bf((v[j] - mean) * rstd * g[e] + bta[e]);
  }
}

// ---------------------------------------------------------------------------
// Flash attention (round-3/7 known-good version).
// ---------------------------------------------------------------------------
template <bool CAUSAL>
__global__ __launch_bounds__(256) void flash_k(
    const unsigned short* __restrict__ Q,
    const unsigned short* __restrict__ K,
    const unsigned short* __restrict__ VT,
    unsigned short* __restrict__ O) {
  __shared__ __align__(16) unsigned short Ks[128 * 64];
  __shared__ __align__(16) unsigned short Vs[64 * 128];
  __shared__ __align__(16) unsigned short Ps[4][32 * 128];

  const int tid = threadIdx.x;
  const int lane = tid & 63;
  const int w = tid >> 6;
  const int lane16 = lane & 15;
  const int l4 = lane >> 4;
  const int bh = blockIdx.y;
  const int b = bh / Hc, h = bh % Hc;
  const int q0 = blockIdx.x * 128;

  const unsigned short* Qb = Q + ((long)b * Tc) * Dc + h * HDc;
  const unsigned short* Kb = K + ((long)b * Tc) * Dc + h * HDc;
  const unsigned short* Vb = VT + (long)bh * HDc * Tc;
  unsigned short* Ob = O + ((long)b * Tc) * Dc + h * HDc;

  bf16x8 qf[2][2];
  #pragma unroll
  for (int m = 0; m < 2; m++)
    #pragma unroll
    for (int kk = 0; kk < 2; kk++) {
      u16x8 raw = *reinterpret_cast<const u16x8*>(
          Qb + (long)(q0 + w * 32 + m * 16 + lane16) * Dc + kk * 32 + l4 * 8);
      bf16x8 f;
      #pragma unroll
      for (int j = 0; j < 8; j++) f[j] = (__bf16)(bf2f(raw[j]) * 0.125f);
      qf[m][kk] = f;
    }

  float mrow[2][4], lrow[2][4];
  f32x4 accO[2][4];
  #pragma unroll
  for (int m = 0; m < 2; m++)
    #pragma unroll
    for (int r = 0; r < 4; r++) { mrow[m][r] = -1e30f; lrow[m][r] = 0.f; }
  #pragma unroll
  for (int m = 0; m < 2; m++)
    #pragma unroll
    for (int d4 = 0; d4 < 4; d4++)
      #pragma unroll
      for (int r = 0; r < 4; r++) accO[m][d4][r] = 0.f;

  const int nch = CAUSAL ? (blockIdx.x + 1) : (Tc / 128);
  for (int c = 0; c < nch; c++) {
    const int k0 = c * 128;
    __syncthreads();
    #pragma unroll
    for (int it = 0; it < 4; it++) {
      int u = (it * 4 + w) * 64 + lane;
      int r = u >> 3, s = u & 7;
      gl_lds16(Kb + (long)(k0 + r) * Dc + ((s ^ (r & 7)) * 8), &Ks[(it * 4 + w) * 512]);
      int r2 = u >> 4, s2 = u & 15;
      gl_lds16(Vb + (long)r2 * Tc + k0 + ((s2 ^ (r2 & 7)) * 8), &Vs[(it * 4 + w) * 512]);
    }
    __syncthreads();

    f32x4 sacc[2][8];
    #pragma unroll
    for (int m = 0; m < 2; m++)
      #pragma unroll
      for (int n = 0; n < 8; n++)
        #pragma unroll
        for (int r = 0; r < 4; r++) sacc[m][n][r] = 0.f;
    #pragma unroll
    for (int n = 0; n < 8; n++) {
      int row = n * 16 + lane16;
      #pragma unroll
      for (int kk = 0; kk < 2; kk++) {
        bf16x8 kf = *reinterpret_cast<const bf16x8*>(
            &Ks[row * 64 + (((kk * 4 + l4) ^ (row & 7)) * 8)]);
        sacc[0][n] = __builtin_amdgcn_mfma_f32_16x16x32_bf16(qf[0][kk], kf, sacc[0][n], 0, 0, 0);
        sacc[1][n] = __builtin_amdgcn_mfma_f32_16x16x32_bf16(qf[1][kk], kf, sacc[1][n], 0, 0, 0);
      }
    }

    if (CAUSAL && c == nch - 1) {
      #pragma unroll
      for (int m = 0; m < 2; m++)
        #pragma unroll
        for (int n = 0; n < 8; n++)
          #pragma unroll
          for (int r = 0; r < 4; r++) {
            int kcol = k0 + n * 16 + lane16;
            int q = q0 + w * 32 + m * 16 + l4 * 4 + r;
            if (kcol > q) sacc[m][n][r] = -1e30f;
          }
    }

    #pragma unroll
    for (int m = 0; m < 2; m++)
      #pragma unroll
      for (int r = 0; r < 4; r++) {
        float smax = sacc[m][0][r];
        #pragma unroll
        for (int n = 1; n < 8; n++) smax = fmaxf(smax, sacc[m][n][r]);
        #pragma unroll
        for (int off = 1; off < 16; off <<= 1) smax = fmaxf(smax, __shfl_xor(smax, off, 64));
        float mold = mrow[m][r];
        float mnew = fmaxf(mold, smax);
        float sc = __expf(mold - mnew);
        float psum = 0.f;
        unsigned short pv[8];
        #pragma unroll
        for (int n = 0; n < 8; n++) {
          float p = __expf(sacc[m][n][r] - mnew);
          psum += p;
          pv[n] = f2bf(p);
        }
        #pragma unroll
        for (int off = 1; off < 16; off <<= 1) psum += __shfl_xor(psum, off, 64);
        lrow[m][r] = lrow[m][r] * sc + psum;
        mrow[m][r] = mnew;
        #pragma unroll
        for (int d4 = 0; d4 < 4; d4++) accO[m][d4][r] *= sc;
        int prow = m * 16 + l4 * 4 + r;
        #pragma unroll
        for (int n = 0; n < 8; n++) {
          int col = n * 16 + lane16;
          Ps[w][prow * 128 + (((col >> 3) ^ (prow & 7)) * 8) + (col & 7)] = pv[n];
        }
      }

    #pragma unroll
    for (int kk = 0; kk < 4; kk++) {
      bf16x8 pa[2];
      #pragma unroll
      for (int m = 0; m < 2; m++) {
        int arow = m * 16 + lane16;
        pa[m] = *reinterpret_cast<const bf16x8*>(
            &Ps[w][arow * 128 + (((kk * 4 + l4) ^ (arow & 7)) * 8)]);
      }
      #pragma unroll
      for (int d4 = 0; d4 < 4; d4++) {
        int vrow = d4 * 16 + lane16;
        bf16x8 vf = *reinterpret_cast<const bf16x8*>(
            &Vs[vrow * 128 + (((kk * 4 + l4) ^ (vrow & 7)) * 8)]);
        accO[0][d4] = __builtin_amdgcn_mfma_f32_16x16x32_bf16(pa[0], vf, accO[0][d4], 0, 0, 0);
        accO[1][d4] = __builtin_amdgcn_mfma_f32_16x16x32_bf16(pa[1], vf, accO[1][d4], 0, 0, 0);
      }
    }
  }

  #pragma unroll
  for (int m = 0; m < 2; m++)
    #pragma unroll
    for (int r = 0; r < 4; r++) {
      float inv = 1.f / lrow[m][r];
      int q = q0 + w * 32 + m * 16 + l4 * 4 + r;
      #pragma unroll
      for (int d4 = 0; d4 < 4; d4++)
        Ob[(long)q * Dc + d4 * 16 + lane16] = f2bf(accO[m][d4][r] * inv);
    }
}

// ---------------------------------------------------------------------------
// Unified MFMA GEMM.  Template BK (32/64); 2 LDS buffers, counted-vmcnt
// pipeline with raw barriers.  4 waves (2Mx2N).  CHUNKG>0: 2D-chunked
// XCD swizzle (R9-verified, LM head).
// ---------------------------------------------------------------------------
template <int BM, int BN, int BK, int MF, int NF, int MINW, int CHUNKG,
          bool HASBIAS, bool RELU, bool HASRES, bool OUTBF>
__global__ __launch_bounds__(256, MINW) void gemm_k(
    const unsigned short* __restrict__ A, long sAb, long sAh, int lda,
    const unsigned short* __restrict__ BT, long sBb, long sBh, int ldb,
    void* Cp, long sCb, long sCh, int ldc,
    const float* __restrict__ bias,
    const float* __restrict__ Res, int ldr,
    const unsigned short* __restrict__ A2,
    int K, int nH, float alpha) {
  constexpr int RPI = 1024 / (2 * BK);          // rows per gl_lds instruction
  constexpr int AI = (BM / 4) / RPI;
  constexpr int BI = (BN / 4) / RPI;
  constexpr int VC = AI + BI;
  __shared__ __align__(16) unsigned short As[2][BM * BK];
  __shared__ __align__(16) unsigned short Bs[2][BN * BK];

  const int tid = threadIdx.x;
  const int lane = tid & 63;
  const int w = tid >> 6;
  const int wr = w >> 1, wc = w & 1;
  const int lane16 = lane & 15;
  const int l4 = lane >> 4;

  const int z = blockIdx.z;
  const int bb = z / nH, hh = z % nH;
  const unsigned short* Abase = (A2 != nullptr && hh != 0) ? A2 : A;
  const long offA = sAb * bb + sAh * hh;
  const long offB = sBb * bb + sBh * hh;
  const long offC = sCb * bb + sCh * hh;

  const int gx = gridDim.x;
  const int gy = gridDim.y;
  const int nwg = gx * gy;
  const int id = blockIdx.y * gx + blockIdx.x;
  const int q8 = nwg >> 3, r8 = nwg & 7;
  const int xcd = id & 7, ord = id >> 3;
  const int swz = (xcd < r8 ? xcd * (q8 + 1) : r8 * (q8 + 1) + (xcd - r8) * q8) + ord;
  int m0, n0;
  if constexpr (CHUNKG > 0) {
    const int span = gy * CHUNKG;
    const int xg = swz / span;
    const int rem = swz - xg * span;
    const int yy = rem / CHUNKG;
    const int xi = rem - yy * CHUNKG;
    m0 = (xg * CHUNKG + xi) * BM;
    n0 = yy * BN;
  } else {
    m0 = (swz % gx) * BM;
    n0 = (swz / gx) * BN;
  }

  int srow, sslot;
  if constexpr (BK == 32) {
    srow = lane >> 2;                               // 16 rows x 4 slots
    sslot = ((lane & 3) ^ ((srow >> 1) & 3)) * 8;
  } else {
    srow = lane >> 3;                               // 8 rows x 8 slots
    sslot = ((lane & 7) ^ (srow & 7)) * 8;
  }

  const unsigned short* aP[AI];
  #pragma unroll
  for (int j = 0; j < AI; j++)
    aP[j] = Abase + offA + (long)(m0 + w * (BM / 4) + j * RPI + srow) * lda + sslot;
  const unsigned short* bP[BI];
  #pragma unroll
  for (int j = 0; j < BI; j++)
    bP[j] = BT + offB + (long)(n0 + w * (BN / 4) + j * RPI + srow) * ldb + sslot;

  f32x4 acc[MF][NF];
  #pragma unroll
  for (int m = 0; m < MF; m++)
    #pragma unroll
    for (int n = 0; n < NF; n++)
      #pragma unroll
      for (int r = 0; r < 4; r++) acc[m][n][r] = 0.f;

  auto STAGE = [&](int buf, int k0) {
    #pragma unroll
    for (int j = 0; j < AI; j++)
      gl_lds16(aP[j] + k0, &As[buf][(w * (BM / 4) + j * RPI) * BK]);
    #pragma unroll
    for (int j = 0; j < BI; j++)
      gl_lds16(bP[j] + k0, &Bs[buf][(w * (BN / 4) + j * RPI) * BK]);
  };

  auto kkey = [&](int row) -> int {
    if constexpr (BK == 32) return (row >> 1) & 3;
    else                    return row & 7;
  };

  const int nt = K / BK;
  STAGE(0, 0);
  int cur = 0;
  for (int t = 0; t < nt; t++) {
    if (t + 1 < nt) { STAGE(cur ^ 1, (t + 1) * BK); wait_vm<VC>(); }
    else            { wait_vm<0>(); }
    __builtin_amdgcn_sched_barrier(0);
    __builtin_amdgcn_s_barrier();
    __builtin_amdgcn_sched_barrier(0);

    #pragma unroll
    for (int kk = 0; kk < BK / 32; kk++) {
      bf16x8 afr[MF], bfr[NF];
      #pragma unroll
      for (int n = 0; n < NF; n++) {
        int row = wc * NF * 16 + n * 16 + lane16;
        bfr[n] = *reinterpret_cast<const bf16x8*>(
            &Bs[cur][row * BK + (((kk * 4 + l4) ^ kkey(row)) * 8)]);
      }
      #pragma unroll
      for (int m = 0; m < MF; m++) {
        int row = wr * MF * 16 + m * 16 + lane16;
        afr[m] = *reinterpret_cast<const bf16x8*>(
            &As[cur][row * BK + (((kk * 4 + l4) ^ kkey(row)) * 8)]);
      }
      __builtin_amdgcn_s_setprio(1);
      #pragma unroll
      for (int m = 0; m < MF; m++)
        #pragma unroll
        for (int n = 0; n < NF; n++)
          acc[m][n] = __builtin_amdgcn_mfma_f32_16x16x32_bf16(afr[m], bfr[n], acc[m][n], 0, 0, 0);
      __builtin_amdgcn_s_setprio(0);
    }

    asm volatile("s_waitcnt lgkmcnt(0)" ::: "memory");
    __builtin_amdgcn_sched_barrier(0);
    __builtin_amdgcn_s_barrier();
    cur ^= 1;
  }

  const int r0 = m0 + wr * MF * 16;
  const int c0 = n0 + wc * NF * 16;
  #pragma unroll
  for (int m = 0; m < MF; m++) {
    #pragma unroll
    for (int n = 0; n < NF; n++) {
      #pragma unroll
      for (int r = 0; r < 4; r++) {
        int rr = r0 + m * 16 + l4 * 4 + r;
        int cc = c0 + n * 16 + lane16;
        float v = acc[m][n][r] * alpha;
        if constexpr (HASBIAS) v += bias[cc];
        if constexpr (RELU) v = fmaxf(v, 0.f);
        if constexpr (HASRES) v += Res[offC + (long)rr * ldr + cc];
        if constexpr (OUTBF) ((unsigned short*)Cp)[offC + (long)rr * ldc + cc] = f2bf(v);
        else                 ((float*)Cp)[offC + (long)rr * ldc + cc] = v;
      }
    }
  }
}

// ---------------------------------------------------------------------------
extern "C" void kernel_launch(void* const* d_in, const int* in_sizes, int n_in,
                              void* d_out, int out_size, void* d_ws, size_t ws_size,
                              hipStream_t stream) {
  (void)in_sizes; (void)n_in; (void)out_size;

  const int*   idx      = (const int*)d_in[0];
  const int*   enc_in   = (const int*)d_in[1];
  const float* enc_tok  = (const float*)d_in[2];
  const float* enc_pos  = (const float*)d_in[3];
  const float* enc_qkv  = (const float*)d_in[4];
  const float* enc_wo   = (const float*)d_in[5];
  const float* enc_bo   = (const float*)d_in[6];
  const float* enc_w1   = (const float*)d_in[7];
  const float* enc_b1   = (const float*)d_in[8];
  const float* enc_w2   = (const float*)d_in[9];
  const float* enc_b2   = (const float*)d_in[10];
  const float* enc_ln1g = (const float*)d_in[11];
  const float* enc_ln1b = (const float*)d_in[12];
  const float* enc_ln2g = (const float*)d_in[13];
  const float* enc_ln2b = (const float*)d_in[14];
  const float* enc_lnfg = (const float*)d_in[15];
  const float* enc_lnfb = (const float*)d_in[16];
  const float* dec_tok  = (const float*)d_in[17];
  const float* dec_pos  = (const float*)d_in[18];
  const float* dec_qkv  = (const float*)d_in[19];
  const float* dec_wo   = (const float*)d_in[20];
  const float* dec_bo   = (const float*)d_in[21];
  const float* dec_cqkv = (const float*)d_in[22];
  const float* dec_cwo  = (const float*)d_in[23];
  const float* dec_cbo  = (const float*)d_in[24];
  const float* dec_w1   = (const float*)d_in[25];
  const float* dec_b1   = (const float*)d_in[26];
  const float* dec_w2   = (const float*)d_in[27];
  const float* dec_b2   = (const float*)d_in[28];
  const float* dec_ln1g = (const float*)d_in[29];
  const float* dec_ln1b = (const float*)d_in[30];
  const float* dec_ln2g = (const float*)d_in[31];
  const float* dec_ln2b = (const float*)d_in[32];
  const float* dec_ln3g = (const float*)d_in[33];
  const float* dec_ln3b = (const float*)d_in[34];
  const float* dec_lnfg = (const float*)d_in[35];
  const float* dec_lnfb = (const float*)d_in[36];
  const float* lm_w     = (const float*)d_in[37];
  const float* lm_b     = (const float*)d_in[38];

  constexpr long De2 = (long)Dc * Dc;
  constexpr long DF  = (long)Dc * FFc;

  // ---- d_out head as weight cache (rewritten every call; LM head writes last) ----
  unsigned short* wcache = (unsigned short*)d_out;
  size_t woff = 0;
  auto take = [&](size_t n) { unsigned short* p = wcache + woff; woff += n; return p; };
  unsigned short* enc_qkvT  = take(18ul * De2);
  unsigned short* enc_woT   = take(6ul * De2);
  unsigned short* enc_w1T   = take(6ul * DF);
  unsigned short* enc_w2T   = take(6ul * DF);
  unsigned short* dec_qkvT  = take(18ul * De2);
  unsigned short* dec_woT   = take(6ul * De2);
  unsigned short* dec_cqkvT = take(18ul * De2);
  unsigned short* dec_cwoT  = take(6ul * De2);
  unsigned short* dec_w1T   = take(6ul * DF);
  unsigned short* dec_w2T   = take(6ul * DF);

  // ---- ws layout ----
  char* ws = (char*)d_ws;
  const size_t need = (size_t)Dc * Vc * 2 + 2ull * Mtot * Dc * 4 + 3ull * Mtot * Dc * 2 +
                      3ull * Mtot * Dc * 2 + (size_t)Mtot * FFc * 2 + (size_t)Mtot * Dc * 2 +
                      (size_t)Bc * Hc * HDc * Tc * 2 + 4096;
  if (ws_size < need) return;
  auto takeW = [&](size_t bytes) { char* p = ws; ws += (bytes + 255) & ~255ull; return p; };
  unsigned short* lm_wT = (unsigned short*)takeW((size_t)Dc * Vc * 2);
  float* xe             = (float*)takeW((size_t)Mtot * Dc * 4);
  float* xd             = (float*)takeW((size_t)Mtot * Dc * 4);
  unsigned short* hbf   = (unsigned short*)takeW((size_t)Mtot * Dc * 2);
  unsigned short* qkvb  = (unsigned short*)takeW(3ull * Mtot * Dc * 2);
  unsigned short* ao    = (unsigned short*)takeW((size_t)Mtot * Dc * 2);
  unsigned short* mid   = (unsigned short*)takeW((size_t)Mtot * FFc * 2);
  unsigned short* eo    = (unsigned short*)takeW((size_t)Mtot * Dc * 2);
  unsigned short* vT    = (unsigned short*)takeW((size_t)Bc * Hc * HDc * Tc * 2);
  unsigned short* qb = qkvb;
  unsigned short* kb = qkvb + (size_t)Mtot * Dc;
  unsigned short* vb = qkvb + 2ull * Mtot * Dc;

  const dim3 TB(256);

  // ---- mega weight conversion (ONE dispatch for all 11 groups) ----
  WcTab tab;
  tab.start[0] = 0;
  auto ent = [&](int i, const float* s, unsigned short* d, int K, int N, int nz) {
    tab.src[i] = s; tab.dst[i] = d; tab.Kt[i] = K / 32; tab.Nt[i] = N / 32;
    tab.start[i + 1] = tab.start[i] + (K / 32) * (N / 32) * nz;
  };
  ent(0,  enc_qkv,  enc_qkvT,  Dc,  Dc, 18);
  ent(1,  enc_wo,   enc_woT,   Dc,  Dc,  6);
  ent(2,  enc_w1,   enc_w1T,   Dc,  FFc, 6);
  ent(3,  enc_w2,   enc_w2T,   FFc, Dc,  6);
  ent(4,  dec_qkv,  dec_qkvT,  Dc,  Dc, 18);
  ent(5,  dec_wo,   dec_woT,   Dc,  Dc,  6);
  ent(6,  dec_cqkv, dec_cqkvT, Dc,  Dc, 18);
  ent(7,  dec_cwo,  dec_cwoT,  Dc,  Dc,  6);
  ent(8,  dec_w1,   dec_w1T,   Dc,  FFc, 6);
  ent(9,  dec_w2,   dec_w2T,   FFc, Dc,  6);
  ent(10, lm_w,     lm_wT,     Dc,  Vc,  1);
  wconv_all_k<<<dim3(tab.start[11]), TB, 0, stream>>>(tab);

  auto LN = [&](const float* X, const float* g, const float* b, unsigned short* o) {
    ln_k<<<dim3(Mtot), TB, 0, stream>>>(X, g, b, o);
  };
  // self-attention QKV: 128x64 @ BK64, 1152 blocks
  auto QKV3 = [&](const unsigned short* Abf, const unsigned short* W3T) {
    gemm_k<128,64,64,4,2,3,0,false,false,false,true>
      <<<dim3(Mtot/128, Dc/64, 3), TB, 0, stream>>>(
        Abf, 0, 0, Dc, W3T, De2, 0, Dc,
        qkvb, (long)Mtot*Dc, 0, Dc, nullptr, nullptr, 0, nullptr, Dc, 1, 1.f);
  };
  // merged cross QKV: 64x64 @ BK64, 2304 blocks, 5 blocks/CU (MINW=5)
  auto CQKV = [&](const unsigned short* Abf, const unsigned short* WcT) {
    gemm_k<64,64,64,2,2,5,0,false,false,false,true>
      <<<dim3(Mtot/64, Dc/64, 3), TB, 0, stream>>>(
        Abf, 0, 0, Dc, WcT, 0, De2, Dc,
        qkvb, 0, (long)Mtot*Dc, Dc, nullptr, nullptr, 0, eo, Dc, 3, 1.f);
  };
  auto VT = [&]() {
    vtrans_k<<<dim3(Tc/64, Bc*Hc), TB, 0, stream>>>(vb, vT);
  };
  auto FLASH = [&](bool causal) {
    if (causal) flash_k<true ><<<dim3(Tc/128, Bc*Hc), TB, 0, stream>>>(qb, kb, vT, ao);
    else        flash_k<false><<<dim3(Tc/128, Bc*Hc), TB, 0, stream>>>(qb, kb, vT, ao);
  };
  // output proj + residual: 64x64 @ BK64, 768 blocks
  auto ORES = [&](const unsigned short* Abf, const unsigned short* WT, const float* bias, float* X) {
    gemm_k<64,64,64,2,2,4,0,true,false,true,false>
      <<<dim3(Mtot/64, Dc/64, 1), TB, 0, stream>>>(
        Abf, 0, 0, Dc, WT, 0, 0, Dc,
        X, 0, 0, Dc, bias, X, Dc, nullptr, Dc, 1, 1.f);
  };
  // FFN1: 128x64 @ BK64, 1536 blocks
  auto FFN1 = [&](const unsigned short* Abf, const unsigned short* WT, const float* bias) {
    gemm_k<128,64,64,4,2,3,0,true,true,false,true>
      <<<dim3(Mtot/128, FFc/64, 1), TB, 0, stream>>>(
        Abf, 0, 0, Dc, WT, 0, 0, Dc,
        mid, 0, 0, FFc, bias, nullptr, 0, nullptr, Dc, 1, 1.f);
  };
  // FFN2: 64x64 @ BK64 (K=3072 -> 48 steps), 768 blocks
  auto FFN2 = [&](const unsigned short* WT, const float* bias, float* X) {
    gemm_k<64,64,64,2,2,4,0,true,false,true,false>
      <<<dim3(Mtot/64, Dc/64, 1), TB, 0, stream>>>(
        mid, 0, 0, FFc, WT, 0, 0, FFc,
        X, 0, 0, Dc, bias, X, Dc, nullptr, FFc, 1, 1.f);
  };

  // ======================= encoder =======================
  embed_k<<<dim3(Mtot), TB, 0, stream>>>(enc_in, enc_tok, enc_pos, xe);
  for (int i = 0; i < Lc; i++) {
    LN(xe, enc_ln1g + i * Dc, enc_ln1b + i * Dc, hbf);
    QKV3(hbf, enc_qkvT + (size_t)i * 3 * De2);
    VT(); FLASH(true);
    ORES(ao, enc_woT + (size_t)i * De2, enc_bo + i * Dc, xe);
    LN(xe, enc_ln2g + i * Dc, enc_ln2b + i * Dc, hbf);
    FFN1(hbf, enc_w1T + (size_t)i * DF, enc_b1 + i * FFc);
    FFN2(enc_w2T + (size_t)i * DF, enc_b2 + i * Dc, xe);
  }
  LN(xe, enc_lnfg, enc_lnfb, eo);

  // ======================= decoder =======================
  embed_k<<<dim3(Mtot), TB, 0, stream>>>(idx, dec_tok, dec_pos, xd);
  for (int i = 0; i < Lc; i++) {
    LN(xd, dec_ln1g + i * Dc, dec_ln1b + i * Dc, hbf);
    QKV3(hbf, dec_qkvT + (size_t)i * 3 * De2);
    VT(); FLASH(true);
    ORES(ao, dec_woT + (size_t)i * De2, dec_bo + i * Dc, xd);
    LN(xd, dec_ln2g + i * Dc, dec_ln2b + i * Dc, hbf);
    CQKV(hbf, dec_cqkvT + (size_t)i * 3 * De2);
    VT(); FLASH(false);
    ORES(ao, dec_cwoT + (size_t)i * De2, dec_cbo + i * Dc, xd);
    LN(xd, dec_ln3g + i * Dc, dec_ln3b + i * Dc, hbf);
    FFN1(hbf, dec_w1T + (size_t)i * DF, dec_b1 + i * FFc);
    FFN2(dec_w2T + (size_t)i * DF, dec_b2 + i * Dc, xd);
  }
  LN(xd, dec_lnfg, dec_lnfb, hbf);

  // ======================= LM head (BK32, MINW=5, chunked swizzle G=16) ====
  gemm_k<128,128,32,4,4,5,16,true,false,false,false>
    <<<dim3(Mtot/128, Vc/128, 1), TB, 0, stream>>>(
      hbf, 0, 0, Dc, lm_wT, 0, 0, Dc,
      d_out, 0, 0, Vc, lm_b, nullptr, 0, nullptr, Dc, 1, 1.f);
}

// Round 13
// 3851.791 us; speedup vs baseline: 1.0841x; 1.0841x over previous
//
#include <hip/hip_runtime.h>

// ---------------------------------------------------------------------------
// GPT encoder-decoder forward on MI355X (gfx950).
// Round 13: exact revert to round-10 configuration (best: 3.848 ms).
// R12's MINW=5 spilled the accumulator (VGPR 56->48, WRITE 513->835MB);
// LM head and CQKV restored to MINW=4.
// ---------------------------------------------------------------------------

typedef __bf16 bf16x8 __attribute__((ext_vector_type(8)));
typedef float  f32x4  __attribute__((ext_vector_type(4)));
typedef unsigned short u16x4 __attribute__((ext_vector_type(4)));
typedef unsigned short u16x8 __attribute__((ext_vector_type(8)));

constexpr int Lc = 6, Dc = 768, Hc = 12, HDc = 64, Vc = 32000;
constexpr int Bc = 4, Tc = 1024, FFc = 3072;
constexpr int Mtot = Bc * Tc;  // 4096

static __device__ __forceinline__ unsigned short f2bf(float f) {
  union { float f; unsigned u; } x; x.f = f;
  unsigned r = x.u + 0x7fffu + ((x.u >> 16) & 1u);   // RNE
  return (unsigned short)(r >> 16);
}
static __device__ __forceinline__ float bf2f(unsigned short s) {
  union { unsigned u; float f; } c; c.u = (unsigned)s << 16; return c.f;
}

static __device__ __forceinline__ void gl_lds16(const unsigned short* g, unsigned short* l) {
  __builtin_amdgcn_global_load_lds(
      (const __attribute__((address_space(1))) unsigned int*)g,
      (__attribute__((address_space(3))) unsigned int*)l, 16, 0, 0);
}

template <int N> static __device__ __forceinline__ void wait_vm() {
  if constexpr (N == 0)       asm volatile("s_waitcnt vmcnt(0)" ::: "memory");
  else if constexpr (N == 2)  asm volatile("s_waitcnt vmcnt(2)" ::: "memory");
  else if constexpr (N == 3)  asm volatile("s_waitcnt vmcnt(3)" ::: "memory");
  else if constexpr (N == 4)  asm volatile("s_waitcnt vmcnt(4)" ::: "memory");
  else if constexpr (N == 6)  asm volatile("s_waitcnt vmcnt(6)" ::: "memory");
  else if constexpr (N == 8)  asm volatile("s_waitcnt vmcnt(8)" ::: "memory");
}

// ---------------------------------------------------------------------------
// Block reductions (256 threads = 4 waves)
// ---------------------------------------------------------------------------
static __device__ __forceinline__ float blockReduceSum(float v, float* red) {
  #pragma unroll
  for (int o = 32; o; o >>= 1) v += __shfl_xor(v, o, 64);
  int w = threadIdx.x >> 6;
  __syncthreads();
  if ((threadIdx.x & 63) == 0) red[w] = v;
  __syncthreads();
  return red[0] + red[1] + red[2] + red[3];
}

// ---------------------------------------------------------------------------
// Mega weight transpose+convert: all 11 weight groups in ONE dispatch.
// ---------------------------------------------------------------------------
struct WcTab {
  const float* src[11];
  unsigned short* dst[11];
  int Kt[11], Nt[11];
  int start[12];
};

__global__ __launch_bounds__(256) void wconv_all_k(WcTab tab) {
  __shared__ float t[32][33];
  const int tb = blockIdx.x;
  int e = 0;
  #pragma unroll
  for (int i = 1; i < 11; i++) if (tb >= tab.start[i]) e = i;
  const int local = tb - tab.start[e];
  const int Kt = tab.Kt[e], Nt = tab.Nt[e];
  const int per = Kt * Nt;
  const int z = local / per;
  const int rem = local - z * per;
  const int k0 = (rem / Nt) * 32, n0 = (rem % Nt) * 32;
  const int K = Kt * 32, N = Nt * 32;
  const float* W = tab.src[e] + (long)z * K * N;
  unsigned short* WT = tab.dst[e] + (long)z * K * N;

  const int tid = threadIdx.x;
  const int rr = tid >> 3;
  const int cc = (tid & 7) * 4;
  f32x4 v = *reinterpret_cast<const f32x4*>(W + (long)(k0 + rr) * N + n0 + cc);
  #pragma unroll
  for (int j = 0; j < 4; j++) t[rr][cc + j] = v[j];
  __syncthreads();
  u16x4 o;
  #pragma unroll
  for (int j = 0; j < 4; j++) o[j] = f2bf(t[cc + j][rr]);
  *reinterpret_cast<u16x4*>(WT + (long)(n0 + rr) * K + k0 + cc) = o;
}

// ---------------------------------------------------------------------------
// V transpose: vb bf16 [B*T][D] (head h cols) -> vT bf16 [B*H][HD][T]
// ---------------------------------------------------------------------------
__global__ __launch_bounds__(256) void vtrans_k(const unsigned short* __restrict__ V,
                                                unsigned short* __restrict__ VT) {
  __shared__ unsigned short t[64][65];
  const int bh = blockIdx.y;
  const int b = bh / Hc, h = bh % Hc;
  const int t0 = blockIdx.x * 64;
  const int tid = threadIdx.x;
  const int rr = tid >> 3;
  const int c8 = (tid & 7) * 8;
  #pragma unroll
  for (int rep = 0; rep < 2; rep++) {
    int row = rep * 32 + rr;
    u16x8 v = *reinterpret_cast<const u16x8*>(V + (long)(b * Tc + t0 + row) * Dc + h * HDc + c8);
    #pragma unroll
    for (int j = 0; j < 8; j++) t[row][c8 + j] = v[j];
  }
  __syncthreads();
  #pragma unroll
  for (int rep = 0; rep < 2; rep++) {
    int hd = rep * 32 + rr;
    u16x8 o;
    #pragma unroll
    for (int j = 0; j < 8; j++) o[j] = t[c8 + j][hd];
    *reinterpret_cast<u16x8*>(VT + ((long)bh * HDc + hd) * Tc + t0 + c8) = o;
  }
}

// ---------------------------------------------------------------------------
// Embedding
// ---------------------------------------------------------------------------
__global__ __launch_bounds__(256) void embed_k(const int* __restrict__ idx,
                                               const float* __restrict__ tok,
                                               const float* __restrict__ pos,
                                               float* __restrict__ out) {
  const long row = blockIdx.x;
  const int t = (int)(row % Tc);
  const long id = idx[row];
  #pragma unroll
  for (int j = 0; j < 3; j++) {
    int e = threadIdx.x + j * 256;
    out[row * Dc + e] = tok[id * Dc + e] + pos[(long)t * Dc + e];
  }
}

// ---------------------------------------------------------------------------
// LayerNorm over D=768, output bf16
// ---------------------------------------------------------------------------
__global__ __launch_bounds__(256) void ln_k(const float* __restrict__ X,
                                            const float* __restrict__ g,
                                            const float* __restrict__ bta,
                                            unsigned short* __restrict__ out) {
  __shared__ float red[4];
  const long row = blockIdx.x;
  const int tid = threadIdx.x;
  float v[3];
  #pragma unroll
  for (int j = 0; j < 3; j++) v[j] = X[row * Dc + tid + j * 256];
  float s = v[0] + v[1] + v[2];
  s = blockReduceSum(s, red);
  float mean = s * (1.f / 768.f);
  float q = 0.f;
  #pragma unroll
  for (int j = 0; j < 3; j++) { float d = v[j] - mean; q += d * d; }
  q = blockReduceSum(q, red);
  float rstd = rsqrtf(q * (1.f / 768.f) + 1e-5f);
  #pragma unroll
  for (int j = 0; j < 3; j++) {
    int e = tid + j * 256;
    out[row * Dc + e] = f2bf((v[j] - mean) * rstd * g[e] + bta[e]);
  }
}

// ---------------------------------------------------------------------------
// Flash attention (round-3/7 known-good version).
// ---------------------------------------------------------------------------
template <bool CAUSAL>
__global__ __launch_bounds__(256) void flash_k(
    const unsigned short* __restrict__ Q,
    const unsigned short* __restrict__ K,
    const unsigned short* __restrict__ VT,
    unsigned short* __restrict__ O) {
  __shared__ __align__(16) unsigned short Ks[128 * 64];
  __shared__ __align__(16) unsigned short Vs[64 * 128];
  __shared__ __align__(16) unsigned short Ps[4][32 * 128];

  const int tid = threadIdx.x;
  const int lane = tid & 63;
  const int w = tid >> 6;
  const int lane16 = lane & 15;
  const int l4 = lane >> 4;
  const int bh = blockIdx.y;
  const int b = bh / Hc, h = bh % Hc;
  const int q0 = blockIdx.x * 128;

  const unsigned short* Qb = Q + ((long)b * Tc) * Dc + h * HDc;
  const unsigned short* Kb = K + ((long)b * Tc) * Dc + h * HDc;
  const unsigned short* Vb = VT + (long)bh * HDc * Tc;
  unsigned short* Ob = O + ((long)b * Tc) * Dc + h * HDc;

  bf16x8 qf[2][2];
  #pragma unroll
  for (int m = 0; m < 2; m++)
    #pragma unroll
    for (int kk = 0; kk < 2; kk++) {
      u16x8 raw = *reinterpret_cast<const u16x8*>(
          Qb + (long)(q0 + w * 32 + m * 16 + lane16) * Dc + kk * 32 + l4 * 8);
      bf16x8 f;
      #pragma unroll
      for (int j = 0; j < 8; j++) f[j] = (__bf16)(bf2f(raw[j]) * 0.125f);
      qf[m][kk] = f;
    }

  float mrow[2][4], lrow[2][4];
  f32x4 accO[2][4];
  #pragma unroll
  for (int m = 0; m < 2; m++)
    #pragma unroll
    for (int r = 0; r < 4; r++) { mrow[m][r] = -1e30f; lrow[m][r] = 0.f; }
  #pragma unroll
  for (int m = 0; m < 2; m++)
    #pragma unroll
    for (int d4 = 0; d4 < 4; d4++)
      #pragma unroll
      for (int r = 0; r < 4; r++) accO[m][d4][r] = 0.f;

  const int nch = CAUSAL ? (blockIdx.x + 1) : (Tc / 128);
  for (int c = 0; c < nch; c++) {
    const int k0 = c * 128;
    __syncthreads();
    #pragma unroll
    for (int it = 0; it < 4; it++) {
      int u = (it * 4 + w) * 64 + lane;
      int r = u >> 3, s = u & 7;
      gl_lds16(Kb + (long)(k0 + r) * Dc + ((s ^ (r & 7)) * 8), &Ks[(it * 4 + w) * 512]);
      int r2 = u >> 4, s2 = u & 15;
      gl_lds16(Vb + (long)r2 * Tc + k0 + ((s2 ^ (r2 & 7)) * 8), &Vs[(it * 4 + w) * 512]);
    }
    __syncthreads();

    f32x4 sacc[2][8];
    #pragma unroll
    for (int m = 0; m < 2; m++)
      #pragma unroll
      for (int n = 0; n < 8; n++)
        #pragma unroll
        for (int r = 0; r < 4; r++) sacc[m][n][r] = 0.f;
    #pragma unroll
    for (int n = 0; n < 8; n++) {
      int row = n * 16 + lane16;
      #pragma unroll
      for (int kk = 0; kk < 2; kk++) {
        bf16x8 kf = *reinterpret_cast<const bf16x8*>(
            &Ks[row * 64 + (((kk * 4 + l4) ^ (row & 7)) * 8)]);
        sacc[0][n] = __builtin_amdgcn_mfma_f32_16x16x32_bf16(qf[0][kk], kf, sacc[0][n], 0, 0, 0);
        sacc[1][n] = __builtin_amdgcn_mfma_f32_16x16x32_bf16(qf[1][kk], kf, sacc[1][n], 0, 0, 0);
      }
    }

    if (CAUSAL && c == nch - 1) {
      #pragma unroll
      for (int m = 0; m < 2; m++)
        #pragma unroll
        for (int n = 0; n < 8; n++)
          #pragma unroll
          for (int r = 0; r < 4; r++) {
            int kcol = k0 + n * 16 + lane16;
            int q = q0 + w * 32 + m * 16 + l4 * 4 + r;
            if (kcol > q) sacc[m][n][r] = -1e30f;
          }
    }

    #pragma unroll
    for (int m = 0; m < 2; m++)
      #pragma unroll
      for (int r = 0; r < 4; r++) {
        float smax = sacc[m][0][r];
        #pragma unroll
        for (int n = 1; n < 8; n++) smax = fmaxf(smax, sacc[m][n][r]);
        #pragma unroll
        for (int off = 1; off < 16; off <<= 1) smax = fmaxf(smax, __shfl_xor(smax, off, 64));
        float mold = mrow[m][r];
        float mnew = fmaxf(mold, smax);
        float sc = __expf(mold - mnew);
        float psum = 0.f;
        unsigned short pv[8];
        #pragma unroll
        for (int n = 0; n < 8; n++) {
          float p = __expf(sacc[m][n][r] - mnew);
          psum += p;
          pv[n] = f2bf(p);
        }
        #pragma unroll
        for (int off = 1; off < 16; off <<= 1) psum += __shfl_xor(psum, off, 64);
        lrow[m][r] = lrow[m][r] * sc + psum;
        mrow[m][r] = mnew;
        #pragma unroll
        for (int d4 = 0; d4 < 4; d4++) accO[m][d4][r] *= sc;
        int prow = m * 16 + l4 * 4 + r;
        #pragma unroll
        for (int n = 0; n < 8; n++) {
          int col = n * 16 + lane16;
          Ps[w][prow * 128 + (((col >> 3) ^ (prow & 7)) * 8) + (col & 7)] = pv[n];
        }
      }

    #pragma unroll
    for (int kk = 0; kk < 4; kk++) {
      bf16x8 pa[2];
      #pragma unroll
      for (int m = 0; m < 2; m++) {
        int arow = m * 16 + lane16;
        pa[m] = *reinterpret_cast<const bf16x8*>(
            &Ps[w][arow * 128 + (((kk * 4 + l4) ^ (arow & 7)) * 8)]);
      }
      #pragma unroll
      for (int d4 = 0; d4 < 4; d4++) {
        int vrow = d4 * 16 + lane16;
        bf16x8 vf = *reinterpret_cast<const bf16x8*>(
            &Vs[vrow * 128 + (((kk * 4 + l4) ^ (vrow & 7)) * 8)]);
        accO[0][d4] = __builtin_amdgcn_mfma_f32_16x16x32_bf16(pa[0], vf, accO[0][d4], 0, 0, 0);
        accO[1][d4] = __builtin_amdgcn_mfma_f32_16x16x32_bf16(pa[1], vf, accO[1][d4], 0, 0, 0);
      }
    }
  }

  #pragma unroll
  for (int m = 0; m < 2; m++)
    #pragma unroll
    for (int r = 0; r < 4; r++) {
      float inv = 1.f / lrow[m][r];
      int q = q0 + w * 32 + m * 16 + l4 * 4 + r;
      #pragma unroll
      for (int d4 = 0; d4 < 4; d4++)
        Ob[(long)q * Dc + d4 * 16 + lane16] = f2bf(accO[m][d4][r] * inv);
    }
}

// ---------------------------------------------------------------------------
// Unified MFMA GEMM.  Template BK (32/64); 2 LDS buffers, counted-vmcnt
// pipeline with raw barriers.  4 waves (2Mx2N).  CHUNKG>0: 2D-chunked
// XCD swizzle (R9-verified, LM head).
// ---------------------------------------------------------------------------
template <int BM, int BN, int BK, int MF, int NF, int MINW, int CHUNKG,
          bool HASBIAS, bool RELU, bool HASRES, bool OUTBF>
__global__ __launch_bounds__(256, MINW) void gemm_k(
    const unsigned short* __restrict__ A, long sAb, long sAh, int lda,
    const unsigned short* __restrict__ BT, long sBb, long sBh, int ldb,
    void* Cp, long sCb, long sCh, int ldc,
    const float* __restrict__ bias,
    const float* __restrict__ Res, int ldr,
    const unsigned short* __restrict__ A2,
    int K, int nH, float alpha) {
  constexpr int RPI = 1024 / (2 * BK);          // rows per gl_lds instruction
  constexpr int AI = (BM / 4) / RPI;
  constexpr int BI = (BN / 4) / RPI;
  constexpr int VC = AI + BI;
  __shared__ __align__(16) unsigned short As[2][BM * BK];
  __shared__ __align__(16) unsigned short Bs[2][BN * BK];

  const int tid = threadIdx.x;
  const int lane = tid & 63;
  const int w = tid >> 6;
  const int wr = w >> 1, wc = w & 1;
  const int lane16 = lane & 15;
  const int l4 = lane >> 4;

  const int z = blockIdx.z;
  const int bb = z / nH, hh = z % nH;
  const unsigned short* Abase = (A2 != nullptr && hh != 0) ? A2 : A;
  const long offA = sAb * bb + sAh * hh;
  const long offB = sBb * bb + sBh * hh;
  const long offC = sCb * bb + sCh * hh;

  const int gx = gridDim.x;
  const int gy = gridDim.y;
  const int nwg = gx * gy;
  const int id = blockIdx.y * gx + blockIdx.x;
  const int q8 = nwg >> 3, r8 = nwg & 7;
  const int xcd = id & 7, ord = id >> 3;
  const int swz = (xcd < r8 ? xcd * (q8 + 1) : r8 * (q8 + 1) + (xcd - r8) * q8) + ord;
  int m0, n0;
  if constexpr (CHUNKG > 0) {
    const int span = gy * CHUNKG;
    const int xg = swz / span;
    const int rem = swz - xg * span;
    const int yy = rem / CHUNKG;
    const int xi = rem - yy * CHUNKG;
    m0 = (xg * CHUNKG + xi) * BM;
    n0 = yy * BN;
  } else {
    m0 = (swz % gx) * BM;
    n0 = (swz / gx) * BN;
  }

  int srow, sslot;
  if constexpr (BK == 32) {
    srow = lane >> 2;                               // 16 rows x 4 slots
    sslot = ((lane & 3) ^ ((srow >> 1) & 3)) * 8;
  } else {
    srow = lane >> 3;                               // 8 rows x 8 slots
    sslot = ((lane & 7) ^ (srow & 7)) * 8;
  }

  const unsigned short* aP[AI];
  #pragma unroll
  for (int j = 0; j < AI; j++)
    aP[j] = Abase + offA + (long)(m0 + w * (BM / 4) + j * RPI + srow) * lda + sslot;
  const unsigned short* bP[BI];
  #pragma unroll
  for (int j = 0; j < BI; j++)
    bP[j] = BT + offB + (long)(n0 + w * (BN / 4) + j * RPI + srow) * ldb + sslot;

  f32x4 acc[MF][NF];
  #pragma unroll
  for (int m = 0; m < MF; m++)
    #pragma unroll
    for (int n = 0; n < NF; n++)
      #pragma unroll
      for (int r = 0; r < 4; r++) acc[m][n][r] = 0.f;

  auto STAGE = [&](int buf, int k0) {
    #pragma unroll
    for (int j = 0; j < AI; j++)
      gl_lds16(aP[j] + k0, &As[buf][(w * (BM / 4) + j * RPI) * BK]);
    #pragma unroll
    for (int j = 0; j < BI; j++)
      gl_lds16(bP[j] + k0, &Bs[buf][(w * (BN / 4) + j * RPI) * BK]);
  };

  auto kkey = [&](int row) -> int {
    if constexpr (BK == 32) return (row >> 1) & 3;
    else                    return row & 7;
  };

  const int nt = K / BK;
  STAGE(0, 0);
  int cur = 0;
  for (int t = 0; t < nt; t++) {
    if (t + 1 < nt) { STAGE(cur ^ 1, (t + 1) * BK); wait_vm<VC>(); }
    else            { wait_vm<0>(); }
    __builtin_amdgcn_sched_barrier(0);
    __builtin_amdgcn_s_barrier();
    __builtin_amdgcn_sched_barrier(0);

    #pragma unroll
    for (int kk = 0; kk < BK / 32; kk++) {
      bf16x8 afr[MF], bfr[NF];
      #pragma unroll
      for (int n = 0; n < NF; n++) {
        int row = wc * NF * 16 + n * 16 + lane16;
        bfr[n] = *reinterpret_cast<const bf16x8*>(
            &Bs[cur][row * BK + (((kk * 4 + l4) ^ kkey(row)) * 8)]);
      }
      #pragma unroll
      for (int m = 0; m < MF; m++) {
        int row = wr * MF * 16 + m * 16 + lane16;
        afr[m] = *reinterpret_cast<const bf16x8*>(
            &As[cur][row * BK + (((kk * 4 + l4) ^ kkey(row)) * 8)]);
      }
      __builtin_amdgcn_s_setprio(1);
      #pragma unroll
      for (int m = 0; m < MF; m++)
        #pragma unroll
        for (int n = 0; n < NF; n++)
          acc[m][n] = __builtin_amdgcn_mfma_f32_16x16x32_bf16(afr[m], bfr[n], acc[m][n], 0, 0, 0);
      __builtin_amdgcn_s_setprio(0);
    }

    asm volatile("s_waitcnt lgkmcnt(0)" ::: "memory");
    __builtin_amdgcn_sched_barrier(0);
    __builtin_amdgcn_s_barrier();
    cur ^= 1;
  }

  const int r0 = m0 + wr * MF * 16;
  const int c0 = n0 + wc * NF * 16;
  #pragma unroll
  for (int m = 0; m < MF; m++) {
    #pragma unroll
    for (int n = 0; n < NF; n++) {
      #pragma unroll
      for (int r = 0; r < 4; r++) {
        int rr = r0 + m * 16 + l4 * 4 + r;
        int cc = c0 + n * 16 + lane16;
        float v = acc[m][n][r] * alpha;
        if constexpr (HASBIAS) v += bias[cc];
        if constexpr (RELU) v = fmaxf(v, 0.f);
        if constexpr (HASRES) v += Res[offC + (long)rr * ldr + cc];
        if constexpr (OUTBF) ((unsigned short*)Cp)[offC + (long)rr * ldc + cc] = f2bf(v);
        else                 ((float*)Cp)[offC + (long)rr * ldc + cc] = v;
      }
    }
  }
}

// ---------------------------------------------------------------------------
extern "C" void kernel_launch(void* const* d_in, const int* in_sizes, int n_in,
                              void* d_out, int out_size, void* d_ws, size_t ws_size,
                              hipStream_t stream) {
  (void)in_sizes; (void)n_in; (void)out_size;

  const int*   idx      = (const int*)d_in[0];
  const int*   enc_in   = (const int*)d_in[1];
  const float* enc_tok  = (const float*)d_in[2];
  const float* enc_pos  = (const float*)d_in[3];
  const float* enc_qkv  = (const float*)d_in[4];
  const float* enc_wo   = (const float*)d_in[5];
  const float* enc_bo   = (const float*)d_in[6];
  const float* enc_w1   = (const float*)d_in[7];
  const float* enc_b1   = (const float*)d_in[8];
  const float* enc_w2   = (const float*)d_in[9];
  const float* enc_b2   = (const float*)d_in[10];
  const float* enc_ln1g = (const float*)d_in[11];
  const float* enc_ln1b = (const float*)d_in[12];
  const float* enc_ln2g = (const float*)d_in[13];
  const float* enc_ln2b = (const float*)d_in[14];
  const float* enc_lnfg = (const float*)d_in[15];
  const float* enc_lnfb = (const float*)d_in[16];
  const float* dec_tok  = (const float*)d_in[17];
  const float* dec_pos  = (const float*)d_in[18];
  const float* dec_qkv  = (const float*)d_in[19];
  const float* dec_wo   = (const float*)d_in[20];
  const float* dec_bo   = (const float*)d_in[21];
  const float* dec_cqkv = (const float*)d_in[22];
  const float* dec_cwo  = (const float*)d_in[23];
  const float* dec_cbo  = (const float*)d_in[24];
  const float* dec_w1   = (const float*)d_in[25];
  const float* dec_b1   = (const float*)d_in[26];
  const float* dec_w2   = (const float*)d_in[27];
  const float* dec_b2   = (const float*)d_in[28];
  const float* dec_ln1g = (const float*)d_in[29];
  const float* dec_ln1b = (const float*)d_in[30];
  const float* dec_ln2g = (const float*)d_in[31];
  const float* dec_ln2b = (const float*)d_in[32];
  const float* dec_ln3g = (const float*)d_in[33];
  const float* dec_ln3b = (const float*)d_in[34];
  const float* dec_lnfg = (const float*)d_in[35];
  const float* dec_lnfb = (const float*)d_in[36];
  const float* lm_w     = (const float*)d_in[37];
  const float* lm_b     = (const float*)d_in[38];

  constexpr long De2 = (long)Dc * Dc;
  constexpr long DF  = (long)Dc * FFc;

  // ---- d_out head as weight cache (rewritten every call; LM head writes last) ----
  unsigned short* wcache = (unsigned short*)d_out;
  size_t woff = 0;
  auto take = [&](size_t n) { unsigned short* p = wcache + woff; woff += n; return p; };
  unsigned short* enc_qkvT  = take(18ul * De2);
  unsigned short* enc_woT   = take(6ul * De2);
  unsigned short* enc_w1T   = take(6ul * DF);
  unsigned short* enc_w2T   = take(6ul * DF);
  unsigned short* dec_qkvT  = take(18ul * De2);
  unsigned short* dec_woT   = take(6ul * De2);
  unsigned short* dec_cqkvT = take(18ul * De2);
  unsigned short* dec_cwoT  = take(6ul * De2);
  unsigned short* dec_w1T   = take(6ul * DF);
  unsigned short* dec_w2T   = take(6ul * DF);

  // ---- ws layout ----
  char* ws = (char*)d_ws;
  const size_t need = (size_t)Dc * Vc * 2 + 2ull * Mtot * Dc * 4 + 3ull * Mtot * Dc * 2 +
                      3ull * Mtot * Dc * 2 + (size_t)Mtot * FFc * 2 + (size_t)Mtot * Dc * 2 +
                      (size_t)Bc * Hc * HDc * Tc * 2 + 4096;
  if (ws_size < need) return;
  auto takeW = [&](size_t bytes) { char* p = ws; ws += (bytes + 255) & ~255ull; return p; };
  unsigned short* lm_wT = (unsigned short*)takeW((size_t)Dc * Vc * 2);
  float* xe             = (float*)takeW((size_t)Mtot * Dc * 4);
  float* xd             = (float*)takeW((size_t)Mtot * Dc * 4);
  unsigned short* hbf   = (unsigned short*)takeW((size_t)Mtot * Dc * 2);
  unsigned short* qkvb  = (unsigned short*)takeW(3ull * Mtot * Dc * 2);
  unsigned short* ao    = (unsigned short*)takeW((size_t)Mtot * Dc * 2);
  unsigned short* mid   = (unsigned short*)takeW((size_t)Mtot * FFc * 2);
  unsigned short* eo    = (unsigned short*)takeW((size_t)Mtot * Dc * 2);
  unsigned short* vT    = (unsigned short*)takeW((size_t)Bc * Hc * HDc * Tc * 2);
  unsigned short* qb = qkvb;
  unsigned short* kb = qkvb + (size_t)Mtot * Dc;
  unsigned short* vb = qkvb + 2ull * Mtot * Dc;

  const dim3 TB(256);

  // ---- mega weight conversion (ONE dispatch for all 11 groups) ----
  WcTab tab;
  tab.start[0] = 0;
  auto ent = [&](int i, const float* s, unsigned short* d, int K, int N, int nz) {
    tab.src[i] = s; tab.dst[i] = d; tab.Kt[i] = K / 32; tab.Nt[i] = N / 32;
    tab.start[i + 1] = tab.start[i] + (K / 32) * (N / 32) * nz;
  };
  ent(0,  enc_qkv,  enc_qkvT,  Dc,  Dc, 18);
  ent(1,  enc_wo,   enc_woT,   Dc,  Dc,  6);
  ent(2,  enc_w1,   enc_w1T,   Dc,  FFc, 6);
  ent(3,  enc_w2,   enc_w2T,   FFc, Dc,  6);
  ent(4,  dec_qkv,  dec_qkvT,  Dc,  Dc, 18);
  ent(5,  dec_wo,   dec_woT,   Dc,  Dc,  6);
  ent(6,  dec_cqkv, dec_cqkvT, Dc,  Dc, 18);
  ent(7,  dec_cwo,  dec_cwoT,  Dc,  Dc,  6);
  ent(8,  dec_w1,   dec_w1T,   Dc,  FFc, 6);
  ent(9,  dec_w2,   dec_w2T,   FFc, Dc,  6);
  ent(10, lm_w,     lm_wT,     Dc,  Vc,  1);
  wconv_all_k<<<dim3(tab.start[11]), TB, 0, stream>>>(tab);

  auto LN = [&](const float* X, const float* g, const float* b, unsigned short* o) {
    ln_k<<<dim3(Mtot), TB, 0, stream>>>(X, g, b, o);
  };
  // self-attention QKV: 128x64 @ BK64, 1152 blocks
  auto QKV3 = [&](const unsigned short* Abf, const unsigned short* W3T) {
    gemm_k<128,64,64,4,2,3,0,false,false,false,true>
      <<<dim3(Mtot/128, Dc/64, 3), TB, 0, stream>>>(
        Abf, 0, 0, Dc, W3T, De2, 0, Dc,
        qkvb, (long)Mtot*Dc, 0, Dc, nullptr, nullptr, 0, nullptr, Dc, 1, 1.f);
  };
  // merged cross QKV: 64x64 @ BK64, 2304 blocks
  auto CQKV = [&](const unsigned short* Abf, const unsigned short* WcT) {
    gemm_k<64,64,64,2,2,4,0,false,false,false,true>
      <<<dim3(Mtot/64, Dc/64, 3), TB, 0, stream>>>(
        Abf, 0, 0, Dc, WcT, 0, De2, Dc,
        qkvb, 0, (long)Mtot*Dc, Dc, nullptr, nullptr, 0, eo, Dc, 3, 1.f);
  };
  auto VT = [&]() {
    vtrans_k<<<dim3(Tc/64, Bc*Hc), TB, 0, stream>>>(vb, vT);
  };
  auto FLASH = [&](bool causal) {
    if (causal) flash_k<true ><<<dim3(Tc/128, Bc*Hc), TB, 0, stream>>>(qb, kb, vT, ao);
    else        flash_k<false><<<dim3(Tc/128, Bc*Hc), TB, 0, stream>>>(qb, kb, vT, ao);
  };
  // output proj + residual: 64x64 @ BK64, 768 blocks
  auto ORES = [&](const unsigned short* Abf, const unsigned short* WT, const float* bias, float* X) {
    gemm_k<64,64,64,2,2,4,0,true,false,true,false>
      <<<dim3(Mtot/64, Dc/64, 1), TB, 0, stream>>>(
        Abf, 0, 0, Dc, WT, 0, 0, Dc,
        X, 0, 0, Dc, bias, X, Dc, nullptr, Dc, 1, 1.f);
  };
  // FFN1: 128x64 @ BK64, 1536 blocks
  auto FFN1 = [&](const unsigned short* Abf, const unsigned short* WT, const float* bias) {
    gemm_k<128,64,64,4,2,3,0,true,true,false,true>
      <<<dim3(Mtot/128, FFc/64, 1), TB, 0, stream>>>(
        Abf, 0, 0, Dc, WT, 0, 0, Dc,
        mid, 0, 0, FFc, bias, nullptr, 0, nullptr, Dc, 1, 1.f);
  };
  // FFN2: 64x64 @ BK64 (K=3072 -> 48 steps), 768 blocks
  auto FFN2 = [&](const unsigned short* WT, const float* bias, float* X) {
    gemm_k<64,64,64,2,2,4,0,true,false,true,false>
      <<<dim3(Mtot/64, Dc/64, 1), TB, 0, stream>>>(
        mid, 0, 0, FFc, WT, 0, 0, FFc,
        X, 0, 0, Dc, bias, X, Dc, nullptr, FFc, 1, 1.f);
  };

  // ======================= encoder =======================
  embed_k<<<dim3(Mtot), TB, 0, stream>>>(enc_in, enc_tok, enc_pos, xe);
  for (int i = 0; i < Lc; i++) {
    LN(xe, enc_ln1g + i * Dc, enc_ln1b + i * Dc, hbf);
    QKV3(hbf, enc_qkvT + (size_t)i * 3 * De2);
    VT(); FLASH(true);
    ORES(ao, enc_woT + (size_t)i * De2, enc_bo + i * Dc, xe);
    LN(xe, enc_ln2g + i * Dc, enc_ln2b + i * Dc, hbf);
    FFN1(hbf, enc_w1T + (size_t)i * DF, enc_b1 + i * FFc);
    FFN2(enc_w2T + (size_t)i * DF, enc_b2 + i * Dc, xe);
  }
  LN(xe, enc_lnfg, enc_lnfb, eo);

  // ======================= decoder =======================
  embed_k<<<dim3(Mtot), TB, 0, stream>>>(idx, dec_tok, dec_pos, xd);
  for (int i = 0; i < Lc; i++) {
    LN(xd, dec_ln1g + i * Dc, dec_ln1b + i * Dc, hbf);
    QKV3(hbf, dec_qkvT + (size_t)i * 3 * De2);
    VT(); FLASH(true);
    ORES(ao, dec_woT + (size_t)i * De2, dec_bo + i * Dc, xd);
    LN(xd, dec_ln2g + i * Dc, dec_ln2b + i * Dc, hbf);
    CQKV(hbf, dec_cqkvT + (size_t)i * 3 * De2);
    VT(); FLASH(false);
    ORES(ao, dec_cwoT + (size_t)i * De2, dec_cbo + i * Dc, xd);
    LN(xd, dec_ln3g + i * Dc, dec_ln3b + i * Dc, hbf);
    FFN1(hbf, dec_w1T + (size_t)i * DF, dec_b1 + i * FFc);
    FFN2(dec_w2T + (size_t)i * DF, dec_b2 + i * Dc, xd);
  }
  LN(xd, dec_lnfg, dec_lnfb, hbf);

  // ======================= LM head (BK32, MINW=4, chunked swizzle G=16) ====
  gemm_k<128,128,32,4,4,4,16,true,false,false,false>
    <<<dim3(Mtot/128, Vc/128, 1), TB, 0, stream>>>(
      hbf, 0, 0, Dc, lm_wT, 0, 0, Dc,
      d_out, 0, 0, Vc, lm_b, nullptr, 0, nullptr, Dc, 1, 1.f);
}

// Round 14
// 3780.969 us; speedup vs baseline: 1.1044x; 1.0187x over previous
//
#include <hip/hip_runtime.h>

// ---------------------------------------------------------------------------
// GPT encoder-decoder forward on MI355X (gfx950).
// Round 14: V-transpose fused into the QKV GEMM epilogue (z==2 blocks write
// vT directly through dead-As LDS; vb round-trip + 18 vtrans dispatches
// deleted).  Everything else identical to R10/R13 best (3.848 ms).
// ---------------------------------------------------------------------------

typedef __bf16 bf16x8 __attribute__((ext_vector_type(8)));
typedef float  f32x4  __attribute__((ext_vector_type(4)));
typedef unsigned short u16x4 __attribute__((ext_vector_type(4)));
typedef unsigned short u16x8 __attribute__((ext_vector_type(8)));

constexpr int Lc = 6, Dc = 768, Hc = 12, HDc = 64, Vc = 32000;
constexpr int Bc = 4, Tc = 1024, FFc = 3072;
constexpr int Mtot = Bc * Tc;  // 4096

static __device__ __forceinline__ unsigned short f2bf(float f) {
  union { float f; unsigned u; } x; x.f = f;
  unsigned r = x.u + 0x7fffu + ((x.u >> 16) & 1u);   // RNE
  return (unsigned short)(r >> 16);
}
static __device__ __forceinline__ float bf2f(unsigned short s) {
  union { unsigned u; float f; } c; c.u = (unsigned)s << 16; return c.f;
}

static __device__ __forceinline__ void gl_lds16(const unsigned short* g, unsigned short* l) {
  __builtin_amdgcn_global_load_lds(
      (const __attribute__((address_space(1))) unsigned int*)g,
      (__attribute__((address_space(3))) unsigned int*)l, 16, 0, 0);
}

template <int N> static __device__ __forceinline__ void wait_vm() {
  if constexpr (N == 0)       asm volatile("s_waitcnt vmcnt(0)" ::: "memory");
  else if constexpr (N == 2)  asm volatile("s_waitcnt vmcnt(2)" ::: "memory");
  else if constexpr (N == 3)  asm volatile("s_waitcnt vmcnt(3)" ::: "memory");
  else if constexpr (N == 4)  asm volatile("s_waitcnt vmcnt(4)" ::: "memory");
  else if constexpr (N == 6)  asm volatile("s_waitcnt vmcnt(6)" ::: "memory");
  else if constexpr (N == 8)  asm volatile("s_waitcnt vmcnt(8)" ::: "memory");
}

// ---------------------------------------------------------------------------
// Block reductions (256 threads = 4 waves)
// ---------------------------------------------------------------------------
static __device__ __forceinline__ float blockReduceSum(float v, float* red) {
  #pragma unroll
  for (int o = 32; o; o >>= 1) v += __shfl_xor(v, o, 64);
  int w = threadIdx.x >> 6;
  __syncthreads();
  if ((threadIdx.x & 63) == 0) red[w] = v;
  __syncthreads();
  return red[0] + red[1] + red[2] + red[3];
}

// ---------------------------------------------------------------------------
// Mega weight transpose+convert: all 11 weight groups in ONE dispatch.
// ---------------------------------------------------------------------------
struct WcTab {
  const float* src[11];
  unsigned short* dst[11];
  int Kt[11], Nt[11];
  int start[12];
};

__global__ __launch_bounds__(256) void wconv_all_k(WcTab tab) {
  __shared__ float t[32][33];
  const int tb = blockIdx.x;
  int e = 0;
  #pragma unroll
  for (int i = 1; i < 11; i++) if (tb >= tab.start[i]) e = i;
  const int local = tb - tab.start[e];
  const int Kt = tab.Kt[e], Nt = tab.Nt[e];
  const int per = Kt * Nt;
  const int z = local / per;
  const int rem = local - z * per;
  const int k0 = (rem / Nt) * 32, n0 = (rem % Nt) * 32;
  const int K = Kt * 32, N = Nt * 32;
  const float* W = tab.src[e] + (long)z * K * N;
  unsigned short* WT = tab.dst[e] + (long)z * K * N;

  const int tid = threadIdx.x;
  const int rr = tid >> 3;
  const int cc = (tid & 7) * 4;
  f32x4 v = *reinterpret_cast<const f32x4*>(W + (long)(k0 + rr) * N + n0 + cc);
  #pragma unroll
  for (int j = 0; j < 4; j++) t[rr][cc + j] = v[j];
  __syncthreads();
  u16x4 o;
  #pragma unroll
  for (int j = 0; j < 4; j++) o[j] = f2bf(t[cc + j][rr]);
  *reinterpret_cast<u16x4*>(WT + (long)(n0 + rr) * K + k0 + cc) = o;
}

// ---------------------------------------------------------------------------
// Embedding
// ---------------------------------------------------------------------------
__global__ __launch_bounds__(256) void embed_k(const int* __restrict__ idx,
                                               const float* __restrict__ tok,
                                               const float* __restrict__ pos,
                                               float* __restrict__ out) {
  const long row = blockIdx.x;
  const int t = (int)(row % Tc);
  const long id = idx[row];
  #pragma unroll
  for (int j = 0; j < 3; j++) {
    int e = threadIdx.x + j * 256;
    out[row * Dc + e] = tok[id * Dc + e] + pos[(long)t * Dc + e];
  }
}

// ---------------------------------------------------------------------------
// LayerNorm over D=768, output bf16
// ---------------------------------------------------------------------------
__global__ __launch_bounds__(256) void ln_k(const float* __restrict__ X,
                                            const float* __restrict__ g,
                                            const float* __restrict__ bta,
                                            unsigned short* __restrict__ out) {
  __shared__ float red[4];
  const long row = blockIdx.x;
  const int tid = threadIdx.x;
  float v[3];
  #pragma unroll
  for (int j = 0; j < 3; j++) v[j] = X[row * Dc + tid + j * 256];
  float s = v[0] + v[1] + v[2];
  s = blockReduceSum(s, red);
  float mean = s * (1.f / 768.f);
  float q = 0.f;
  #pragma unroll
  for (int j = 0; j < 3; j++) { float d = v[j] - mean; q += d * d; }
  q = blockReduceSum(q, red);
  float rstd = rsqrtf(q * (1.f / 768.f) + 1e-5f);
  #pragma unroll
  for (int j = 0; j < 3; j++) {
    int e = tid + j * 256;
    out[row * Dc + e] = f2bf((v[j] - mean) * rstd * g[e] + bta[e]);
  }
}

// ---------------------------------------------------------------------------
// Flash attention (round-3/7 known-good version).
// ---------------------------------------------------------------------------
template <bool CAUSAL>
__global__ __launch_bounds__(256) void flash_k(
    const unsigned short* __restrict__ Q,
    const unsigned short* __restrict__ K,
    const unsigned short* __restrict__ VT,
    unsigned short* __restrict__ O) {
  __shared__ __align__(16) unsigned short Ks[128 * 64];
  __shared__ __align__(16) unsigned short Vs[64 * 128];
  __shared__ __align__(16) unsigned short Ps[4][32 * 128];

  const int tid = threadIdx.x;
  const int lane = tid & 63;
  const int w = tid >> 6;
  const int lane16 = lane & 15;
  const int l4 = lane >> 4;
  const int bh = blockIdx.y;
  const int b = bh / Hc, h = bh % Hc;
  const int q0 = blockIdx.x * 128;

  const unsigned short* Qb = Q + ((long)b * Tc) * Dc + h * HDc;
  const unsigned short* Kb = K + ((long)b * Tc) * Dc + h * HDc;
  const unsigned short* Vb = VT + (long)bh * HDc * Tc;
  unsigned short* Ob = O + ((long)b * Tc) * Dc + h * HDc;

  bf16x8 qf[2][2];
  #pragma unroll
  for (int m = 0; m < 2; m++)
    #pragma unroll
    for (int kk = 0; kk < 2; kk++) {
      u16x8 raw = *reinterpret_cast<const u16x8*>(
          Qb + (long)(q0 + w * 32 + m * 16 + lane16) * Dc + kk * 32 + l4 * 8);
      bf16x8 f;
      #pragma unroll
      for (int j = 0; j < 8; j++) f[j] = (__bf16)(bf2f(raw[j]) * 0.125f);
      qf[m][kk] = f;
    }

  float mrow[2][4], lrow[2][4];
  f32x4 accO[2][4];
  #pragma unroll
  for (int m = 0; m < 2; m++)
    #pragma unroll
    for (int r = 0; r < 4; r++) { mrow[m][r] = -1e30f; lrow[m][r] = 0.f; }
  #pragma unroll
  for (int m = 0; m < 2; m++)
    #pragma unroll
    for (int d4 = 0; d4 < 4; d4++)
      #pragma unroll
      for (int r = 0; r < 4; r++) accO[m][d4][r] = 0.f;

  const int nch = CAUSAL ? (blockIdx.x + 1) : (Tc / 128);
  for (int c = 0; c < nch; c++) {
    const int k0 = c * 128;
    __syncthreads();
    #pragma unroll
    for (int it = 0; it < 4; it++) {
      int u = (it * 4 + w) * 64 + lane;
      int r = u >> 3, s = u & 7;
      gl_lds16(Kb + (long)(k0 + r) * Dc + ((s ^ (r & 7)) * 8), &Ks[(it * 4 + w) * 512]);
      int r2 = u >> 4, s2 = u & 15;
      gl_lds16(Vb + (long)r2 * Tc + k0 + ((s2 ^ (r2 & 7)) * 8), &Vs[(it * 4 + w) * 512]);
    }
    __syncthreads();

    f32x4 sacc[2][8];
    #pragma unroll
    for (int m = 0; m < 2; m++)
      #pragma unroll
      for (int n = 0; n < 8; n++)
        #pragma unroll
        for (int r = 0; r < 4; r++) sacc[m][n][r] = 0.f;
    #pragma unroll
    for (int n = 0; n < 8; n++) {
      int row = n * 16 + lane16;
      #pragma unroll
      for (int kk = 0; kk < 2; kk++) {
        bf16x8 kf = *reinterpret_cast<const bf16x8*>(
            &Ks[row * 64 + (((kk * 4 + l4) ^ (row & 7)) * 8)]);
        sacc[0][n] = __builtin_amdgcn_mfma_f32_16x16x32_bf16(qf[0][kk], kf, sacc[0][n], 0, 0, 0);
        sacc[1][n] = __builtin_amdgcn_mfma_f32_16x16x32_bf16(qf[1][kk], kf, sacc[1][n], 0, 0, 0);
      }
    }

    if (CAUSAL && c == nch - 1) {
      #pragma unroll
      for (int m = 0; m < 2; m++)
        #pragma unroll
        for (int n = 0; n < 8; n++)
          #pragma unroll
          for (int r = 0; r < 4; r++) {
            int kcol = k0 + n * 16 + lane16;
            int q = q0 + w * 32 + m * 16 + l4 * 4 + r;
            if (kcol > q) sacc[m][n][r] = -1e30f;
          }
    }

    #pragma unroll
    for (int m = 0; m < 2; m++)
      #pragma unroll
      for (int r = 0; r < 4; r++) {
        float smax = sacc[m][0][r];
        #pragma unroll
        for (int n = 1; n < 8; n++) smax = fmaxf(smax, sacc[m][n][r]);
        #pragma unroll
        for (int off = 1; off < 16; off <<= 1) smax = fmaxf(smax, __shfl_xor(smax, off, 64));
        float mold = mrow[m][r];
        float mnew = fmaxf(mold, smax);
        float sc = __expf(mold - mnew);
        float psum = 0.f;
        unsigned short pv[8];
        #pragma unroll
        for (int n = 0; n < 8; n++) {
          float p = __expf(sacc[m][n][r] - mnew);
          psum += p;
          pv[n] = f2bf(p);
        }
        #pragma unroll
        for (int off = 1; off < 16; off <<= 1) psum += __shfl_xor(psum, off, 64);
        lrow[m][r] = lrow[m][r] * sc + psum;
        mrow[m][r] = mnew;
        #pragma unroll
        for (int d4 = 0; d4 < 4; d4++) accO[m][d4][r] *= sc;
        int prow = m * 16 + l4 * 4 + r;
        #pragma unroll
        for (int n = 0; n < 8; n++) {
          int col = n * 16 + lane16;
          Ps[w][prow * 128 + (((col >> 3) ^ (prow & 7)) * 8) + (col & 7)] = pv[n];
        }
      }

    #pragma unroll
    for (int kk = 0; kk < 4; kk++) {
      bf16x8 pa[2];
      #pragma unroll
      for (int m = 0; m < 2; m++) {
        int arow = m * 16 + lane16;
        pa[m] = *reinterpret_cast<const bf16x8*>(
            &Ps[w][arow * 128 + (((kk * 4 + l4) ^ (arow & 7)) * 8)]);
      }
      #pragma unroll
      for (int d4 = 0; d4 < 4; d4++) {
        int vrow = d4 * 16 + lane16;
        bf16x8 vf = *reinterpret_cast<const bf16x8*>(
            &Vs[vrow * 128 + (((kk * 4 + l4) ^ (vrow & 7)) * 8)]);
        accO[0][d4] = __builtin_amdgcn_mfma_f32_16x16x32_bf16(pa[0], vf, accO[0][d4], 0, 0, 0);
        accO[1][d4] = __builtin_amdgcn_mfma_f32_16x16x32_bf16(pa[1], vf, accO[1][d4], 0, 0, 0);
      }
    }
  }

  #pragma unroll
  for (int m = 0; m < 2; m++)
    #pragma unroll
    for (int r = 0; r < 4; r++) {
      float inv = 1.f / lrow[m][r];
      int q = q0 + w * 32 + m * 16 + l4 * 4 + r;
      #pragma unroll
      for (int d4 = 0; d4 < 4; d4++)
        Ob[(long)q * Dc + d4 * 16 + lane16] = f2bf(accO[m][d4][r] * inv);
    }
}

// ---------------------------------------------------------------------------
// Unified MFMA GEMM.  Template BK (32/64); 2 LDS buffers, counted-vmcnt
// pipeline with raw barriers.  4 waves (2Mx2N).  CHUNKG>0: 2D-chunked
// XCD swizzle.  VWRITE: blocks with z==2 write their output TRANSPOSED to
// Vt[(b*H+h)*HD + hd][t] via dead-As LDS (BN must be 64, n-tiles head-
// aligned, BM<=128 so the m-tile stays within one batch).
// ---------------------------------------------------------------------------
template <int BM, int BN, int BK, int MF, int NF, int MINW, int CHUNKG,
          bool HASBIAS, bool RELU, bool HASRES, bool OUTBF, bool VWRITE>
__global__ __launch_bounds__(256, MINW) void gemm_k(
    const unsigned short* __restrict__ A, long sAb, long sAh, int lda,
    const unsigned short* __restrict__ BT, long sBb, long sBh, int ldb,
    void* Cp, long sCb, long sCh, int ldc,
    const float* __restrict__ bias,
    const float* __restrict__ Res, int ldr,
    const unsigned short* __restrict__ A2,
    unsigned short* __restrict__ Vt,
    int K, int nH, float alpha) {
  constexpr int RPI = 1024 / (2 * BK);          // rows per gl_lds instruction
  constexpr int AI = (BM / 4) / RPI;
  constexpr int BI = (BN / 4) / RPI;
  constexpr int VC = AI + BI;
  __shared__ __align__(16) unsigned short As[2][BM * BK];
  __shared__ __align__(16) unsigned short Bs[2][BN * BK];

  const int tid = threadIdx.x;
  const int lane = tid & 63;
  const int w = tid >> 6;
  const int wr = w >> 1, wc = w & 1;
  const int lane16 = lane & 15;
  const int l4 = lane >> 4;

  const int z = blockIdx.z;
  const int bb = z / nH, hh = z % nH;
  const unsigned short* Abase = (A2 != nullptr && hh != 0) ? A2 : A;
  const long offA = sAb * bb + sAh * hh;
  const long offB = sBb * bb + sBh * hh;
  const long offC = sCb * bb + sCh * hh;

  const int gx = gridDim.x;
  const int gy = gridDim.y;
  const int nwg = gx * gy;
  const int id = blockIdx.y * gx + blockIdx.x;
  const int q8 = nwg >> 3, r8 = nwg & 7;
  const int xcd = id & 7, ord = id >> 3;
  const int swz = (xcd < r8 ? xcd * (q8 + 1) : r8 * (q8 + 1) + (xcd - r8) * q8) + ord;
  int m0, n0;
  if constexpr (CHUNKG > 0) {
    const int span = gy * CHUNKG;
    const int xg = swz / span;
    const int rem = swz - xg * span;
    const int yy = rem / CHUNKG;
    const int xi = rem - yy * CHUNKG;
    m0 = (xg * CHUNKG + xi) * BM;
    n0 = yy * BN;
  } else {
    m0 = (swz % gx) * BM;
    n0 = (swz / gx) * BN;
  }

  int srow, sslot;
  if constexpr (BK == 32) {
    srow = lane >> 2;                               // 16 rows x 4 slots
    sslot = ((lane & 3) ^ ((srow >> 1) & 3)) * 8;
  } else {
    srow = lane >> 3;                               // 8 rows x 8 slots
    sslot = ((lane & 7) ^ (srow & 7)) * 8;
  }

  const unsigned short* aP[AI];
  #pragma unroll
  for (int j = 0; j < AI; j++)
    aP[j] = Abase + offA + (long)(m0 + w * (BM / 4) + j * RPI + srow) * lda + sslot;
  const unsigned short* bP[BI];
  #pragma unroll
  for (int j = 0; j < BI; j++)
    bP[j] = BT + offB + (long)(n0 + w * (BN / 4) + j * RPI + srow) * ldb + sslot;

  f32x4 acc[MF][NF];
  #pragma unroll
  for (int m = 0; m < MF; m++)
    #pragma unroll
    for (int n = 0; n < NF; n++)
      #pragma unroll
      for (int r = 0; r < 4; r++) acc[m][n][r] = 0.f;

  auto STAGE = [&](int buf, int k0) {
    #pragma unroll
    for (int j = 0; j < AI; j++)
      gl_lds16(aP[j] + k0, &As[buf][(w * (BM / 4) + j * RPI) * BK]);
    #pragma unroll
    for (int j = 0; j < BI; j++)
      gl_lds16(bP[j] + k0, &Bs[buf][(w * (BN / 4) + j * RPI) * BK]);
  };

  auto kkey = [&](int row) -> int {
    if constexpr (BK == 32) return (row >> 1) & 3;
    else                    return row & 7;
  };

  const int nt = K / BK;
  STAGE(0, 0);
  int cur = 0;
  for (int t = 0; t < nt; t++) {
    if (t + 1 < nt) { STAGE(cur ^ 1, (t + 1) * BK); wait_vm<VC>(); }
    else            { wait_vm<0>(); }
    __builtin_amdgcn_sched_barrier(0);
    __builtin_amdgcn_s_barrier();
    __builtin_amdgcn_sched_barrier(0);

    #pragma unroll
    for (int kk = 0; kk < BK / 32; kk++) {
      bf16x8 afr[MF], bfr[NF];
      #pragma unroll
      for (int n = 0; n < NF; n++) {
        int row = wc * NF * 16 + n * 16 + lane16;
        bfr[n] = *reinterpret_cast<const bf16x8*>(
            &Bs[cur][row * BK + (((kk * 4 + l4) ^ kkey(row)) * 8)]);
      }
      #pragma unroll
      for (int m = 0; m < MF; m++) {
        int row = wr * MF * 16 + m * 16 + lane16;
        afr[m] = *reinterpret_cast<const bf16x8*>(
            &As[cur][row * BK + (((kk * 4 + l4) ^ kkey(row)) * 8)]);
      }
      __builtin_amdgcn_s_setprio(1);
      #pragma unroll
      for (int m = 0; m < MF; m++)
        #pragma unroll
        for (int n = 0; n < NF; n++)
          acc[m][n] = __builtin_amdgcn_mfma_f32_16x16x32_bf16(afr[m], bfr[n], acc[m][n], 0, 0, 0);
      __builtin_amdgcn_s_setprio(0);
    }

    asm volatile("s_waitcnt lgkmcnt(0)" ::: "memory");
    __builtin_amdgcn_sched_barrier(0);
    __builtin_amdgcn_s_barrier();
    cur ^= 1;
  }

  // ---- VWRITE path: z==2 blocks emit transposed V through dead-As LDS ----
  if constexpr (VWRITE) {
    if (z == 2) {
      unsigned short* T = (unsigned short*)&As[0][0];   // BM x 68 (pad)
      #pragma unroll
      for (int m = 0; m < MF; m++)
        #pragma unroll
        for (int n = 0; n < NF; n++)
          #pragma unroll
          for (int r = 0; r < 4; r++) {
            int rl = wr * MF * 16 + m * 16 + l4 * 4 + r;
            int cl = wc * NF * 16 + n * 16 + lane16;
            T[rl * 68 + cl] = f2bf(acc[m][n][r]);
          }
      __syncthreads();
      const int b = m0 >> 10, t0loc = m0 & 1023, h = n0 >> 6;
      unsigned short* ob = Vt + ((long)(b * Hc + h) * HDc) * Tc;
      const int hd = tid >> 2;      // 0..63
      const int sb = tid & 3;
      #pragma unroll
      for (int v8 = 0; v8 < BM / 32; v8++) {
        int tt = (sb + v8 * 4) * 8;
        u16x8 o;
        #pragma unroll
        for (int e = 0; e < 8; e++) o[e] = T[(tt + e) * 68 + hd];
        *reinterpret_cast<u16x8*>(ob + (long)hd * Tc + t0loc + tt) = o;
      }
      return;
    }
  }

  const int r0 = m0 + wr * MF * 16;
  const int c0 = n0 + wc * NF * 16;
  #pragma unroll
  for (int m = 0; m < MF; m++) {
    #pragma unroll
    for (int n = 0; n < NF; n++) {
      #pragma unroll
      for (int r = 0; r < 4; r++) {
        int rr = r0 + m * 16 + l4 * 4 + r;
        int cc = c0 + n * 16 + lane16;
        float v = acc[m][n][r] * alpha;
        if constexpr (HASBIAS) v += bias[cc];
        if constexpr (RELU) v = fmaxf(v, 0.f);
        if constexpr (HASRES) v += Res[offC + (long)rr * ldr + cc];
        if constexpr (OUTBF) ((unsigned short*)Cp)[offC + (long)rr * ldc + cc] = f2bf(v);
        else                 ((float*)Cp)[offC + (long)rr * ldc + cc] = v;
      }
    }
  }
}

// ---------------------------------------------------------------------------
extern "C" void kernel_launch(void* const* d_in, const int* in_sizes, int n_in,
                              void* d_out, int out_size, void* d_ws, size_t ws_size,
                              hipStream_t stream) {
  (void)in_sizes; (void)n_in; (void)out_size;

  const int*   idx      = (const int*)d_in[0];
  const int*   enc_in   = (const int*)d_in[1];
  const float* enc_tok  = (const float*)d_in[2];
  const float* enc_pos  = (const float*)d_in[3];
  const float* enc_qkv  = (const float*)d_in[4];
  const float* enc_wo   = (const float*)d_in[5];
  const float* enc_bo   = (const float*)d_in[6];
  const float* enc_w1   = (const float*)d_in[7];
  const float* enc_b1   = (const float*)d_in[8];
  const float* enc_w2   = (const float*)d_in[9];
  const float* enc_b2   = (const float*)d_in[10];
  const float* enc_ln1g = (const float*)d_in[11];
  const float* enc_ln1b = (const float*)d_in[12];
  const float* enc_ln2g = (const float*)d_in[13];
  const float* enc_ln2b = (const float*)d_in[14];
  const float* enc_lnfg = (const float*)d_in[15];
  const float* enc_lnfb = (const float*)d_in[16];
  const float* dec_tok  = (const float*)d_in[17];
  const float* dec_pos  = (const float*)d_in[18];
  const float* dec_qkv  = (const float*)d_in[19];
  const float* dec_wo   = (const float*)d_in[20];
  const float* dec_bo   = (const float*)d_in[21];
  const float* dec_cqkv = (const float*)d_in[22];
  const float* dec_cwo  = (const float*)d_in[23];
  const float* dec_cbo  = (const float*)d_in[24];
  const float* dec_w1   = (const float*)d_in[25];
  const float* dec_b1   = (const float*)d_in[26];
  const float* dec_w2   = (const float*)d_in[27];
  const float* dec_b2   = (const float*)d_in[28];
  const float* dec_ln1g = (const float*)d_in[29];
  const float* dec_ln1b = (const float*)d_in[30];
  const float* dec_ln2g = (const float*)d_in[31];
  const float* dec_ln2b = (const float*)d_in[32];
  const float* dec_ln3g = (const float*)d_in[33];
  const float* dec_ln3b = (const float*)d_in[34];
  const float* dec_lnfg = (const float*)d_in[35];
  const float* dec_lnfb = (const float*)d_in[36];
  const float* lm_w     = (const float*)d_in[37];
  const float* lm_b     = (const float*)d_in[38];

  constexpr long De2 = (long)Dc * Dc;
  constexpr long DF  = (long)Dc * FFc;

  // ---- d_out head as weight cache (rewritten every call; LM head writes last) ----
  unsigned short* wcache = (unsigned short*)d_out;
  size_t woff = 0;
  auto take = [&](size_t n) { unsigned short* p = wcache + woff; woff += n; return p; };
  unsigned short* enc_qkvT  = take(18ul * De2);
  unsigned short* enc_woT   = take(6ul * De2);
  unsigned short* enc_w1T   = take(6ul * DF);
  unsigned short* enc_w2T   = take(6ul * DF);
  unsigned short* dec_qkvT  = take(18ul * De2);
  unsigned short* dec_woT   = take(6ul * De2);
  unsigned short* dec_cqkvT = take(18ul * De2);
  unsigned short* dec_cwoT  = take(6ul * De2);
  unsigned short* dec_w1T   = take(6ul * DF);
  unsigned short* dec_w2T   = take(6ul * DF);

  // ---- ws layout ----
  char* ws = (char*)d_ws;
  const size_t need = (size_t)Dc * Vc * 2 + 2ull * Mtot * Dc * 4 + 3ull * Mtot * Dc * 2 +
                      3ull * Mtot * Dc * 2 + (size_t)Mtot * FFc * 2 + (size_t)Mtot * Dc * 2 +
                      (size_t)Bc * Hc * HDc * Tc * 2 + 4096;
  if (ws_size < need) return;
  auto takeW = [&](size_t bytes) { char* p = ws; ws += (bytes + 255) & ~255ull; return p; };
  unsigned short* lm_wT = (unsigned short*)takeW((size_t)Dc * Vc * 2);
  float* xe             = (float*)takeW((size_t)Mtot * Dc * 4);
  float* xd             = (float*)takeW((size_t)Mtot * Dc * 4);
  unsigned short* hbf   = (unsigned short*)takeW((size_t)Mtot * Dc * 2);
  unsigned short* qkvb  = (unsigned short*)takeW(3ull * Mtot * Dc * 2);
  unsigned short* ao    = (unsigned short*)takeW((size_t)Mtot * Dc * 2);
  unsigned short* mid   = (unsigned short*)takeW((size_t)Mtot * FFc * 2);
  unsigned short* eo    = (unsigned short*)takeW((size_t)Mtot * Dc * 2);
  unsigned short* vT    = (unsigned short*)takeW((size_t)Bc * Hc * HDc * Tc * 2);
  unsigned short* qb = qkvb;
  unsigned short* kb = qkvb + (size_t)Mtot * Dc;

  const dim3 TB(256);

  // ---- mega weight conversion (ONE dispatch for all 11 groups) ----
  WcTab tab;
  tab.start[0] = 0;
  auto ent = [&](int i, const float* s, unsigned short* d, int K, int N, int nz) {
    tab.src[i] = s; tab.dst[i] = d; tab.Kt[i] = K / 32; tab.Nt[i] = N / 32;
    tab.start[i + 1] = tab.start[i] + (K / 32) * (N / 32) * nz;
  };
  ent(0,  enc_qkv,  enc_qkvT,  Dc,  Dc, 18);
  ent(1,  enc_wo,   enc_woT,   Dc,  Dc,  6);
  ent(2,  enc_w1,   enc_w1T,   Dc,  FFc, 6);
  ent(3,  enc_w2,   enc_w2T,   FFc, Dc,  6);
  ent(4,  dec_qkv,  dec_qkvT,  Dc,  Dc, 18);
  ent(5,  dec_wo,   dec_woT,   Dc,  Dc,  6);
  ent(6,  dec_cqkv, dec_cqkvT, Dc,  Dc, 18);
  ent(7,  dec_cwo,  dec_cwoT,  Dc,  Dc,  6);
  ent(8,  dec_w1,   dec_w1T,   Dc,  FFc, 6);
  ent(9,  dec_w2,   dec_w2T,   FFc, Dc,  6);
  ent(10, lm_w,     lm_wT,     Dc,  Vc,  1);
  wconv_all_k<<<dim3(tab.start[11]), TB, 0, stream>>>(tab);

  auto LN = [&](const float* X, const float* g, const float* b, unsigned short* o) {
    ln_k<<<dim3(Mtot), TB, 0, stream>>>(X, g, b, o);
  };
  // self-attention QKV: 128x64 @ BK64, 1152 blocks; z==2 (V) writes vT direct
  auto QKV3 = [&](const unsigned short* Abf, const unsigned short* W3T) {
    gemm_k<128,64,64,4,2,3,0,false,false,false,true,true>
      <<<dim3(Mtot/128, Dc/64, 3), TB, 0, stream>>>(
        Abf, 0, 0, Dc, W3T, De2, 0, Dc,
        qkvb, (long)Mtot*Dc, 0, Dc, nullptr, nullptr, 0, nullptr, vT, Dc, 1, 1.f);
  };
  // merged cross QKV: 64x64 @ BK64, 2304 blocks; z==2 (V) writes vT direct
  auto CQKV = [&](const unsigned short* Abf, const unsigned short* WcT) {
    gemm_k<64,64,64,2,2,4,0,false,false,false,true,true>
      <<<dim3(Mtot/64, Dc/64, 3), TB, 0, stream>>>(
        Abf, 0, 0, Dc, WcT, 0, De2, Dc,
        qkvb, 0, (long)Mtot*Dc, Dc, nullptr, nullptr, 0, eo, vT, Dc, 3, 1.f);
  };
  auto FLASH = [&](bool causal) {
    if (causal) flash_k<true ><<<dim3(Tc/128, Bc*Hc), TB, 0, stream>>>(qb, kb, vT, ao);
    else        flash_k<false><<<dim3(Tc/128, Bc*Hc), TB, 0, stream>>>(qb, kb, vT, ao);
  };
  // output proj + residual: 64x64 @ BK64, 768 blocks
  auto ORES = [&](const unsigned short* Abf, const unsigned short* WT, const float* bias, float* X) {
    gemm_k<64,64,64,2,2,4,0,true,false,true,false,false>
      <<<dim3(Mtot/64, Dc/64, 1), TB, 0, stream>>>(
        Abf, 0, 0, Dc, WT, 0, 0, Dc,
        X, 0, 0, Dc, bias, X, Dc, nullptr, nullptr, Dc, 1, 1.f);
  };
  // FFN1: 128x64 @ BK64, 1536 blocks
  auto FFN1 = [&](const unsigned short* Abf, const unsigned short* WT, const float* bias) {
    gemm_k<128,64,64,4,2,3,0,true,true,false,true,false>
      <<<dim3(Mtot/128, FFc/64, 1), TB, 0, stream>>>(
        Abf, 0, 0, Dc, WT, 0, 0, Dc,
        mid, 0, 0, FFc, bias, nullptr, 0, nullptr, nullptr, Dc, 1, 1.f);
  };
  // FFN2: 64x64 @ BK64 (K=3072 -> 48 steps), 768 blocks
  auto FFN2 = [&](const unsigned short* WT, const float* bias, float* X) {
    gemm_k<64,64,64,2,2,4,0,true,false,true,false,false>
      <<<dim3(Mtot/64, Dc/64, 1), TB, 0, stream>>>(
        mid, 0, 0, FFc, WT, 0, 0, FFc,
        X, 0, 0, Dc, bias, X, Dc, nullptr, nullptr, FFc, 1, 1.f);
  };

  // ======================= encoder =======================
  embed_k<<<dim3(Mtot), TB, 0, stream>>>(enc_in, enc_tok, enc_pos, xe);
  for (int i = 0; i < Lc; i++) {
    LN(xe, enc_ln1g + i * Dc, enc_ln1b + i * Dc, hbf);
    QKV3(hbf, enc_qkvT + (size_t)i * 3 * De2);
    FLASH(true);
    ORES(ao, enc_woT + (size_t)i * De2, enc_bo + i * Dc, xe);
    LN(xe, enc_ln2g + i * Dc, enc_ln2b + i * Dc, hbf);
    FFN1(hbf, enc_w1T + (size_t)i * DF, enc_b1 + i * FFc);
    FFN2(enc_w2T + (size_t)i * DF, enc_b2 + i * Dc, xe);
  }
  LN(xe, enc_lnfg, enc_lnfb, eo);

  // ======================= decoder =======================
  embed_k<<<dim3(Mtot), TB, 0, stream>>>(idx, dec_tok, dec_pos, xd);
  for (int i = 0; i < Lc; i++) {
    LN(xd, dec_ln1g + i * Dc, dec_ln1b + i * Dc, hbf);
    QKV3(hbf, dec_qkvT + (size_t)i * 3 * De2);
    FLASH(true);
    ORES(ao, dec_woT + (size_t)i * De2, dec_bo + i * Dc, xd);
    LN(xd, dec_ln2g + i * Dc, dec_ln2b + i * Dc, hbf);
    CQKV(hbf, dec_cqkvT + (size_t)i * 3 * De2);
    FLASH(false);
    ORES(ao, dec_cwoT + (size_t)i * De2, dec_cbo + i * Dc, xd);
    LN(xd, dec_ln3g + i * Dc, dec_ln3b + i * Dc, hbf);
    FFN1(hbf, dec_w1T + (size_t)i * DF, dec_b1 + i * FFc);
    FFN2(dec_w2T + (size_t)i * DF, dec_b2 + i * Dc, xd);
  }
  LN(xd, dec_lnfg, dec_lnfb, hbf);

  // ======================= LM head (BK32, MINW=4, chunked swizzle G=16) ====
  gemm_k<128,128,32,4,4,4,16,true,false,false,false,false>
    <<<dim3(Mtot/128, Vc/128, 1), TB, 0, stream>>>(
      hbf, 0, 0, Dc, lm_wT, 0, 0, Dc,
      d_out, 0, 0, Vc, lm_b, nullptr, 0, nullptr, nullptr, Dc, 1, 1.f);
}